// Round 2
// baseline (2280.158 us; speedup 1.0000x reference)
//
#include <hip/hip_runtime.h>
#include <math.h>

#define E_EDGES 524288
#define N_NODES 32768
#define N_GRAPHS 64
#define NPG 512

typedef unsigned long long u64;

// ---------------- EdgeConv layer 1: gather + [E,8]@[8,64] + stats ----------------
__global__ __launch_bounds__(256) void ec1_kernel(
    const float* __restrict__ x, const int* __restrict__ src, const int* __restrict__ dst,
    const float* __restrict__ W, const float* __restrict__ b,
    float* __restrict__ y, float* __restrict__ sum, float* __restrict__ sq)
{
  __shared__ float Ws[512];
  __shared__ float bs[64];
  __shared__ float red[256];
  int tid = threadIdx.x;
  for (int i = tid; i < 512; i += 256) Ws[i] = W[i];
  if (tid < 64) bs[tid] = b[tid];
  __syncthreads();
  int c = tid & 63;
  int eslot = tid >> 6;
  float ls = 0.f, lq = 0.f;
  int stride = gridDim.x * 4;
  for (int e = blockIdx.x * 4 + eslot; e < E_EDGES; e += stride) {
    int s = src[e], d = dst[e];
    float m[8];
#pragma unroll
    for (int k = 0; k < 4; ++k) {
      float xi = x[d * 4 + k];
      float xj = x[s * 4 + k];
      m[k] = xi; m[4 + k] = xj - xi;
    }
    float acc = bs[c];
#pragma unroll
    for (int k = 0; k < 8; ++k) acc = fmaf(m[k], Ws[k * 64 + c], acc);
    y[(u64)e * 64 + c] = acc;
    ls += acc; lq += acc * acc;
  }
  red[tid] = ls; __syncthreads();
  if (tid < 64) atomicAdd(&sum[tid], red[tid] + red[tid + 64] + red[tid + 128] + red[tid + 192]);
  __syncthreads();
  red[tid] = lq; __syncthreads();
  if (tid < 64) atomicAdd(&sq[tid], red[tid] + red[tid + 64] + red[tid + 128] + red[tid + 192]);
}

// ---------------- stats -> scale/shift ----------------
__global__ void finstats_kernel(const float* __restrict__ sum, const float* __restrict__ sq,
                                float invcnt, const float* __restrict__ g, const float* __restrict__ be,
                                float* __restrict__ sc, float* __restrict__ sh, int C)
{
  int c = threadIdx.x + blockIdx.x * blockDim.x;
  if (c >= C) return;
  float m = sum[c] * invcnt;
  float v = sq[c] * invcnt - m * m;
  float inv = rsqrtf(v + 1e-5f);
  float s = g[c] * inv;
  sc[c] = s;
  sh[c] = fmaf(-m, s, be[c]);
}

// ---------------- generic tiled GEMM: Y = preact(A (+Add)) @ W + b, optional stats ----
// preact(v) = relu(v*preSc[k] + preSh[k]) if preSc != null else v
// NOTE: A and Y may alias (in-place) when gridDim.y == 1: each block reads only its
// own BM rows (all reads complete before the post-loop __syncthreads) and writes only
// those rows in the epilogue. No __restrict__ on A/Y for that reason.
template<int TM, int TN>
__global__ __launch_bounds__(256) void gemm_bn_kernel(
    const float* A, int lda,
    const float* __restrict__ Add, int ldadd,
    const float* __restrict__ preSc, const float* __restrict__ preSh,
    const float* __restrict__ W, const float* __restrict__ bias,
    float* Y, int ldy,
    float* __restrict__ sum, float* __restrict__ sq,
    int M, int K, int Cout)
{
  constexpr int BM = 16 * TM, BN = 16 * TN, BK = 16;
  __shared__ float As[BM * (BK + 1)];
  __shared__ float Ws[BK * (BN + 1)];
  __shared__ float red[16 * BN];
  int tid = threadIdx.x;
  int tx = tid & 15, ty = tid >> 4;
  int row0 = blockIdx.x * BM;
  int col0 = blockIdx.y * BN;
  float acc[TM][TN];
#pragma unroll
  for (int i = 0; i < TM; ++i)
#pragma unroll
    for (int j = 0; j < TN; ++j) acc[i][j] = 0.f;

  for (int k0 = 0; k0 < K; k0 += BK) {
    // load A tile (with optional addend + pre-activation)
    for (int idx = tid * 4; idx < BM * BK; idx += 1024) {
      int r = idx >> 4;
      int kk = idx & 15;
      int grow = row0 + r;
      float4 v = {0.f, 0.f, 0.f, 0.f};
      if (grow < M) {
        v = *(const float4*)(A + (u64)grow * lda + k0 + kk);
        if (Add) {
          float4 a2 = *(const float4*)(Add + (u64)grow * ldadd + k0 + kk);
          v.x += a2.x; v.y += a2.y; v.z += a2.z; v.w += a2.w;
        }
        if (preSc) {
          float4 s4 = *(const float4*)(preSc + k0 + kk);
          float4 h4 = *(const float4*)(preSh + k0 + kk);
          v.x = fmaxf(fmaf(v.x, s4.x, h4.x), 0.f);
          v.y = fmaxf(fmaf(v.y, s4.y, h4.y), 0.f);
          v.z = fmaxf(fmaf(v.z, s4.z, h4.z), 0.f);
          v.w = fmaxf(fmaf(v.w, s4.w, h4.w), 0.f);
        }
      }
      float* p = &As[r * (BK + 1) + kk];
      p[0] = v.x; p[1] = v.y; p[2] = v.z; p[3] = v.w;
    }
    // load W tile
    for (int idx = tid * 4; idx < BK * BN; idx += 1024) {
      int kk = idx / BN;
      int cc = idx % BN;
      int gc = col0 + cc;
      float4 v = {0.f, 0.f, 0.f, 0.f};
      const float* wp = W + (u64)(k0 + kk) * Cout + gc;
      if (gc + 3 < Cout) v = *(const float4*)wp;
      else {
        if (gc + 0 < Cout) v.x = wp[0];
        if (gc + 1 < Cout) v.y = wp[1];
        if (gc + 2 < Cout) v.z = wp[2];
      }
      float* p = &Ws[kk * (BN + 1) + cc];
      p[0] = v.x; p[1] = v.y; p[2] = v.z; p[3] = v.w;
    }
    __syncthreads();
#pragma unroll
    for (int kk = 0; kk < BK; ++kk) {
      float a[TM], w[TN];
#pragma unroll
      for (int j = 0; j < TN; ++j) w[j] = Ws[kk * (BN + 1) + tx * TN + j];
#pragma unroll
      for (int i = 0; i < TM; ++i) a[i] = As[(ty * TM + i) * (BK + 1) + kk];
#pragma unroll
      for (int i = 0; i < TM; ++i)
#pragma unroll
        for (int j = 0; j < TN; ++j) acc[i][j] = fmaf(a[i], w[j], acc[i][j]);
    }
    __syncthreads();
  }
  // epilogue: bias, store, stats
  float bl[TN];
  int cbase = col0 + tx * TN;
#pragma unroll
  for (int j = 0; j < TN; ++j) bl[j] = (cbase + j < Cout) ? bias[cbase + j] : 0.f;
  float csY[TN], csQ[TN];
#pragma unroll
  for (int j = 0; j < TN; ++j) { csY[j] = 0.f; csQ[j] = 0.f; }
#pragma unroll
  for (int i = 0; i < TM; ++i) {
    int grow = row0 + ty * TM + i;
    if (grow < M) {
#pragma unroll
      for (int j = 0; j < TN; ++j) {
        float v = acc[i][j] + bl[j];
        if (cbase + j < Cout) Y[(u64)grow * ldy + cbase + j] = v;
        csY[j] += v; csQ[j] += v * v;
      }
    }
  }
  if (sum) {
    __syncthreads();
#pragma unroll
    for (int j = 0; j < TN; ++j) red[ty * BN + tx * TN + j] = csY[j];
    __syncthreads();
    if (tid < BN) {
      float t = 0.f;
#pragma unroll
      for (int r = 0; r < 16; ++r) t += red[r * BN + tid];
      if (col0 + tid < Cout) atomicAdd(&sum[col0 + tid], t);
    }
    __syncthreads();
#pragma unroll
    for (int j = 0; j < TN; ++j) red[ty * BN + tx * TN + j] = csQ[j];
    __syncthreads();
    if (tid < BN) {
      float t = 0.f;
#pragma unroll
      for (int r = 0; r < 16; ++r) t += red[r * BN + tid];
      if (col0 + tid < Cout) atomicAdd(&sq[col0 + tid], t);
    }
  }
}

// ---------------- in-place act (bn+relu) + stats of result ----------------
__global__ __launch_bounds__(256) void act_stats_kernel(
    float* __restrict__ y, const float* __restrict__ sc, const float* __restrict__ sh,
    float* __restrict__ sum, float* __restrict__ sq, int total, int cmask)
{
  __shared__ float red[256];
  int tid = threadIdx.x;
  int c = tid & cmask;  // gridDim*256 is a multiple of (cmask+1)
  float s = sc[c], b = sh[c];
  float ls = 0.f, lq = 0.f;
  for (int idx = blockIdx.x * 256 + tid; idx < total; idx += gridDim.x * 256) {
    float v = fmaxf(fmaf(y[idx], s, b), 0.f);
    y[idx] = v;
    ls += v; lq += v * v;
  }
  red[tid] = ls; __syncthreads();
  if (tid <= cmask) {
    float t = 0.f;
    for (int k = tid; k < 256; k += cmask + 1) t += red[k];
    atomicAdd(&sum[tid], t);
  }
  __syncthreads();
  red[tid] = lq; __syncthreads();
  if (tid <= cmask) {
    float t = 0.f;
    for (int k = tid; k < 256; k += cmask + 1) t += red[k];
    atomicAdd(&sq[tid], t);
  }
}

// ---------------- apply outer BN into h slice ----------------
__global__ __launch_bounds__(256) void apply_bn_kernel(
    const float* __restrict__ a, const float* __restrict__ sc, const float* __restrict__ sh,
    float* __restrict__ h, int off, int cshift, int cmask, int total)
{
  for (int idx = blockIdx.x * 256 + threadIdx.x; idx < total; idx += gridDim.x * 256) {
    int r = idx >> cshift;
    int c = idx & cmask;
    h[(u64)r * 512 + off + c] = fmaf(a[idx], sc[c], sh[c]);
  }
}

// ---------------- EdgeConv segment_max (relu'd values >= 0 -> int atomicMax) ------
__global__ __launch_bounds__(256) void x0max_kernel(
    const float* __restrict__ y3, const float* __restrict__ sc, const float* __restrict__ sh,
    const int* __restrict__ dst, float* __restrict__ h)
{
  const u64 total = (u64)E_EDGES * 64;
  for (u64 idx = (u64)blockIdx.x * 256 + threadIdx.x; idx < total; idx += (u64)gridDim.x * 256) {
    int e = (int)(idx >> 6);
    int c = (int)(idx & 63);
    float v = fmaxf(fmaf(y3[idx], sc[c], sh[c]), 0.f);
    atomicMax((int*)(h + (u64)dst[e] * 512 + c), __float_as_int(v));
  }
}

// ---------------- GIN segment_sum scatter ----------------
__global__ __launch_bounds__(256) void scatter_add_kernel(
    const float* __restrict__ h, int off, int cshift, int cmask,
    const int* __restrict__ src, const int* __restrict__ dst,
    float* __restrict__ agg, u64 total)
{
  for (u64 idx = (u64)blockIdx.x * 256 + threadIdx.x; idx < total; idx += (u64)gridDim.x * 256) {
    int e = (int)(idx >> cshift);
    int c = (int)(idx & cmask);
    atomicAdd(agg + ((u64)dst[e] << cshift) + c, h[(u64)src[e] * 512 + off + c]);
  }
}

// ---------------- graph pooling (batch = repeat(arange(64),512): dense ranges) ----
__global__ __launch_bounds__(256) void pool_kernel(
    const float* __restrict__ hl, const float* __restrict__ sc, const float* __restrict__ sh,
    float* __restrict__ o)
{
  int g = blockIdx.x;
  int c = blockIdx.y * 256 + threadIdx.x;  // 0..1023
  float s = sc[c], b = sh[c];
  const float* p = hl + (u64)g * NPG * 1024 + c;
  float mx = 0.f, sm = 0.f;
  for (int n = 0; n < NPG; ++n) {
    float v = fmaxf(fmaf(p[(u64)n * 1024], s, b), 0.f);
    mx = fmaxf(mx, v);
    sm += v;
  }
  o[g * 2048 + c] = mx;
  o[g * 2048 + 1024 + c] = sm * (1.f / NPG);
}

// ---------------- log_softmax over 40 cols ----------------
__global__ void lsm_kernel(const float* __restrict__ logits, float* __restrict__ out)
{
  int r = blockIdx.x;
  int c = threadIdx.x;  // 64 threads (1 wave)
  float v = (c < 40) ? logits[r * 40 + c] : -INFINITY;
  float m = v;
  for (int off = 32; off; off >>= 1) m = fmaxf(m, __shfl_xor(m, off, 64));
  float e = (c < 40) ? expf(v - m) : 0.f;
  float s = e;
  for (int off = 32; off; off >>= 1) s += __shfl_xor(s, off, 64);
  if (c < 40) out[r * 40 + c] = (v - m) - logf(s);
}

extern "C" void kernel_launch(void* const* d_in, const int* in_sizes, int n_in,
                              void* d_out, int out_size, void* d_ws, size_t ws_size,
                              hipStream_t stream)
{
  const float* x    = (const float*)d_in[0];
  const int*   ei   = (const int*)d_in[1];
  const int*   srcI = ei;
  const int*   dstI = ei + E_EDGES;
  const float* ecW1 = (const float*)d_in[3];
  const float* ecb1 = (const float*)d_in[4];
  const float* ecg1 = (const float*)d_in[5];
  const float* ecbe1= (const float*)d_in[6];
  const float* ecW2 = (const float*)d_in[7];
  const float* ecb2 = (const float*)d_in[8];
  const float* ecg2 = (const float*)d_in[9];
  const float* ecbe2= (const float*)d_in[10];
  const float* ecW3 = (const float*)d_in[11];
  const float* ecb3 = (const float*)d_in[12];
  const float* ecg3 = (const float*)d_in[13];
  const float* ecbe3= (const float*)d_in[14];
  const float* g1W  = (const float*)d_in[15];
  const float* g1b  = (const float*)d_in[16];
  const float* g1g  = (const float*)d_in[17];
  const float* g1be = (const float*)d_in[18];
  const float* g2W  = (const float*)d_in[19];
  const float* g2b  = (const float*)d_in[20];
  const float* g2g  = (const float*)d_in[21];
  const float* g2be = (const float*)d_in[22];
  const float* g3W  = (const float*)d_in[23];
  const float* g3b  = (const float*)d_in[24];
  const float* g3g  = (const float*)d_in[25];
  const float* g3be = (const float*)d_in[26];
  const float* bn1g = (const float*)d_in[27];
  const float* bn1be= (const float*)d_in[28];
  const float* bn2g = (const float*)d_in[29];
  const float* bn2be= (const float*)d_in[30];
  const float* bn3g = (const float*)d_in[31];
  const float* bn3be= (const float*)d_in[32];
  const float* linW = (const float*)d_in[33];
  const float* linb = (const float*)d_in[34];
  const float* ling = (const float*)d_in[35];
  const float* linbe= (const float*)d_in[36];
  const float* h1W  = (const float*)d_in[37];
  const float* h1b  = (const float*)d_in[38];
  const float* h1g  = (const float*)d_in[39];
  const float* h1be = (const float*)d_in[40];
  const float* h2W  = (const float*)d_in[41];
  const float* h2b  = (const float*)d_in[42];
  const float* h2g  = (const float*)d_in[43];
  const float* h2be = (const float*)d_in[44];
  const float* outW = (const float*)d_in[45];
  const float* outb = (const float*)d_in[46];

  char* ws = (char*)d_ws;
  const size_t MB = 1024ull * 1024ull;
  // ---- small area [0, 1 MiB) ----
  float* sum    = (float*)(ws);                                   // 4 KiB
  float* sq     = (float*)(ws + 4096);                            // 4 KiB
  float* sc     = (float*)(ws + 8192);                            // 4 KiB
  float* sh     = (float*)(ws + 12288);                           // 4 KiB
  float* o_     = (float*)(ws + 16384);                           // [64,2048] 512 KiB
  float* yh1    = (float*)(ws + 16384 + 524288);                  // [64,512] 128 KiB
  float* yh2    = (float*)(ws + 16384 + 524288 + 131072);         // [64,256]  64 KiB
  float* logits = (float*)(ws + 16384 + 524288 + 131072 + 65536); // [64,40]
  // ---- Y region [1 MiB, 129 MiB): edge buffer [E,64] fp32 (in-place through EC);
  //      later: GIN temps (ytemp 32 MiB + agg 32 MiB); later: hl [N,1024] fp32 ----
  float* y     = (float*)(ws + 1 * MB);
  float* ytemp = y;                                   // [N,<=256] fp32, <=32 MiB
  float* agg   = (float*)(ws + 1 * MB + 32 * MB);     // [N,<=256] fp32, <=32 MiB
  float* hl    = y;                                   // [N,1024] fp32, 128 MiB
  // ---- h region [129 MiB, 193 MiB): [N,512] fp32 concat buffer ----
  float* h = (float*)(ws + 129 * MB);
  // total footprint: 193 MiB

#define ZZ(p, n) hipMemsetAsync((void*)(p), 0, (size_t)(n), stream)

  // ---------------- EdgeConv (all in-place in y) ----------------
  ZZ(sum, 8192);
  ec1_kernel<<<512, 256, 0, stream>>>(x, srcI, dstI, ecW1, ecb1, y, sum, sq);
  finstats_kernel<<<1, 1024, 0, stream>>>(sum, sq, 1.f / E_EDGES, ecg1, ecbe1, sc, sh, 64);
  ZZ(sum, 8192);
  gemm_bn_kernel<8, 4><<<dim3(E_EDGES / 128, 1), 256, 0, stream>>>(
      y, 64, nullptr, 0, sc, sh, ecW2, ecb2, y, 64, sum, sq, E_EDGES, 64, 64);
  finstats_kernel<<<1, 1024, 0, stream>>>(sum, sq, 1.f / E_EDGES, ecg2, ecbe2, sc, sh, 64);
  ZZ(sum, 8192);
  gemm_bn_kernel<8, 4><<<dim3(E_EDGES / 128, 1), 256, 0, stream>>>(
      y, 64, nullptr, 0, sc, sh, ecW3, ecb3, y, 64, sum, sq, E_EDGES, 64, 64);
  finstats_kernel<<<1, 1024, 0, stream>>>(sum, sq, 1.f / E_EDGES, ecg3, ecbe3, sc, sh, 64);
  ZZ(h, (size_t)N_NODES * 512 * 4);  // zero h (x0 atomicMax target)
  x0max_kernel<<<8192, 256, 0, stream>>>(y, sc, sh, dstI, h);

  // ---------------- GIN 1: x0(64)@off0 -> x1(64)@off64 ----------------
  ZZ(agg, (size_t)N_NODES * 64 * 4);
  scatter_add_kernel<<<8192, 256, 0, stream>>>(h, 0, 6, 63, srcI, dstI, agg, (u64)E_EDGES * 64);
  ZZ(sum, 8192);
  gemm_bn_kernel<8, 4><<<dim3(N_NODES / 128, 1), 256, 0, stream>>>(
      h, 512, agg, 64, nullptr, nullptr, g1W, g1b, ytemp, 64, sum, sq, N_NODES, 64, 64);
  finstats_kernel<<<1, 1024, 0, stream>>>(sum, sq, 1.f / N_NODES, g1g, g1be, sc, sh, 64);
  ZZ(sum, 8192);
  act_stats_kernel<<<512, 256, 0, stream>>>(ytemp, sc, sh, sum, sq, N_NODES * 64, 63);
  finstats_kernel<<<1, 1024, 0, stream>>>(sum, sq, 1.f / N_NODES, bn1g, bn1be, sc, sh, 64);
  apply_bn_kernel<<<1024, 256, 0, stream>>>(ytemp, sc, sh, h, 64, 6, 63, N_NODES * 64);

  // ---------------- GIN 2: x1(64)@off64 -> x2(128)@off128 ----------------
  ZZ(agg, (size_t)N_NODES * 64 * 4);
  scatter_add_kernel<<<8192, 256, 0, stream>>>(h, 64, 6, 63, srcI, dstI, agg, (u64)E_EDGES * 64);
  ZZ(sum, 8192);
  gemm_bn_kernel<8, 4><<<dim3(N_NODES / 128, 2), 256, 0, stream>>>(
      h + 64, 512, agg, 64, nullptr, nullptr, g2W, g2b, ytemp, 128, sum, sq, N_NODES, 64, 128);
  finstats_kernel<<<1, 1024, 0, stream>>>(sum, sq, 1.f / N_NODES, g2g, g2be, sc, sh, 128);
  ZZ(sum, 8192);
  act_stats_kernel<<<512, 256, 0, stream>>>(ytemp, sc, sh, sum, sq, N_NODES * 128, 127);
  finstats_kernel<<<1, 1024, 0, stream>>>(sum, sq, 1.f / N_NODES, bn2g, bn2be, sc, sh, 128);
  apply_bn_kernel<<<1024, 256, 0, stream>>>(ytemp, sc, sh, h, 128, 7, 127, N_NODES * 128);

  // ---------------- GIN 3: x2(128)@off128 -> x3(256)@off256 ----------------
  ZZ(agg, (size_t)N_NODES * 128 * 4);
  scatter_add_kernel<<<8192, 256, 0, stream>>>(h, 128, 7, 127, srcI, dstI, agg, (u64)E_EDGES * 128);
  ZZ(sum, 8192);
  gemm_bn_kernel<8, 4><<<dim3(N_NODES / 128, 4), 256, 0, stream>>>(
      h + 128, 512, agg, 128, nullptr, nullptr, g3W, g3b, ytemp, 256, sum, sq, N_NODES, 128, 256);
  finstats_kernel<<<1, 1024, 0, stream>>>(sum, sq, 1.f / N_NODES, g3g, g3be, sc, sh, 256);
  ZZ(sum, 8192);
  act_stats_kernel<<<512, 256, 0, stream>>>(ytemp, sc, sh, sum, sq, N_NODES * 256, 255);
  finstats_kernel<<<1, 1024, 0, stream>>>(sum, sq, 1.f / N_NODES, bn3g, bn3be, sc, sh, 256);
  apply_bn_kernel<<<1024, 256, 0, stream>>>(ytemp, sc, sh, h, 256, 8, 255, N_NODES * 256);

  // ---------------- lin: [N,512] @ [512,1024] + stats; pool ----------------
  ZZ(sum, 8192);
  gemm_bn_kernel<8, 8><<<dim3(N_NODES / 128, 1024 / 128), 256, 0, stream>>>(
      h, 512, nullptr, 0, nullptr, nullptr, linW, linb, hl, 1024, sum, sq, N_NODES, 512, 1024);
  finstats_kernel<<<1, 1024, 0, stream>>>(sum, sq, 1.f / N_NODES, ling, linbe, sc, sh, 1024);
  pool_kernel<<<dim3(64, 4), 256, 0, stream>>>(hl, sc, sh, o_);

  // ---------------- head ----------------
  ZZ(sum, 8192);
  gemm_bn_kernel<4, 4><<<dim3(1, 8), 256, 0, stream>>>(
      o_, 2048, nullptr, 0, nullptr, nullptr, h1W, h1b, yh1, 512, sum, sq, 64, 2048, 512);
  finstats_kernel<<<1, 1024, 0, stream>>>(sum, sq, 1.f / 64, h1g, h1be, sc, sh, 512);
  ZZ(sum, 8192);
  gemm_bn_kernel<4, 4><<<dim3(1, 4), 256, 0, stream>>>(
      yh1, 512, nullptr, 0, sc, sh, h2W, h2b, yh2, 256, sum, sq, 64, 512, 256);
  finstats_kernel<<<1, 1024, 0, stream>>>(sum, sq, 1.f / 64, h2g, h2be, sc, sh, 256);
  gemm_bn_kernel<4, 4><<<dim3(1, 1), 256, 0, stream>>>(
      yh2, 256, nullptr, 0, sc, sh, outW, outb, logits, 40, nullptr, nullptr, 64, 256, 40);
  lsm_kernel<<<64, 64, 0, stream>>>(logits, (float*)d_out);
#undef ZZ
}

// Round 4
// 1875.697 us; speedup vs baseline: 1.2156x; 1.2156x over previous
//
#include <hip/hip_runtime.h>
#include <math.h>

#define E_EDGES 524288
#define N_NODES 32768
#define N_GRAPHS 64
#define NPG 512

typedef unsigned long long u64;
using bf16x8 = __attribute__((ext_vector_type(8))) short;
using f32x4  = __attribute__((ext_vector_type(4))) float;

__device__ __forceinline__ unsigned short f2bf(float f) {
  unsigned int u = __float_as_uint(f);
  u += 0x7FFFu + ((u >> 16) & 1u);
  return (unsigned short)(u >> 16);
}
__device__ __forceinline__ float b2f(unsigned short s) {
  return __uint_as_float(((unsigned int)s) << 16);
}

// ---------------- weight transpose + split-bf16 cast ----------------
// Wt_hi[n*K+k] + Wt_lo[n*K+k] ~= W[k*N+n] to ~2^-17 relative
__global__ __launch_bounds__(256) void wt_kernel(
    const float* __restrict__ W, unsigned short* __restrict__ Wt_hi,
    unsigned short* __restrict__ Wt_lo, int kshift, int N, int total)
{
  int idx = blockIdx.x * 256 + threadIdx.x;
  if (idx >= total) return;
  int n = idx >> kshift;
  int k = idx & ((1 << kshift) - 1);
  float w = W[(u64)k * N + n];
  unsigned short hi = f2bf(w);
  Wt_hi[idx] = hi;
  Wt_lo[idx] = f2bf(w - b2f(hi));
}

// ---------------- EdgeConv layer 1: gather + [E,8]@[8,64] + stats (fp32 out) ----
__global__ __launch_bounds__(256) void ec1_kernel(
    const float* __restrict__ x, const int* __restrict__ src, const int* __restrict__ dst,
    const float* __restrict__ W, const float* __restrict__ b,
    float* __restrict__ y, float* __restrict__ sum, float* __restrict__ sq)
{
  __shared__ float Ws[512];
  __shared__ float bs[64];
  __shared__ float red[256];
  int tid = threadIdx.x;
  for (int i = tid; i < 512; i += 256) Ws[i] = W[i];
  if (tid < 64) bs[tid] = b[tid];
  __syncthreads();
  int c = tid & 63;
  int eslot = tid >> 6;
  float ls = 0.f, lq = 0.f;
  int stride = gridDim.x * 4;
  for (int e = blockIdx.x * 4 + eslot; e < E_EDGES; e += stride) {
    int s = src[e], d = dst[e];
    float m[8];
#pragma unroll
    for (int k = 0; k < 4; ++k) {
      float xi = x[d * 4 + k];
      float xj = x[s * 4 + k];
      m[k] = xi; m[4 + k] = xj - xi;
    }
    float acc = bs[c];
#pragma unroll
    for (int k = 0; k < 8; ++k) acc = fmaf(m[k], Ws[k * 64 + c], acc);
    y[(u64)e * 64 + c] = acc;
    ls += acc; lq += acc * acc;
  }
  red[tid] = ls; __syncthreads();
  if (tid < 64) atomicAdd(&sum[tid], red[tid] + red[tid + 64] + red[tid + 128] + red[tid + 192]);
  __syncthreads();
  red[tid] = lq; __syncthreads();
  if (tid < 64) atomicAdd(&sq[tid], red[tid] + red[tid + 64] + red[tid + 128] + red[tid + 192]);
}

// ---------------- stats -> scale/shift ----------------
__global__ void finstats_kernel(const float* __restrict__ sum, const float* __restrict__ sq,
                                float invcnt, const float* __restrict__ g, const float* __restrict__ be,
                                float* __restrict__ sc, float* __restrict__ sh, int C)
{
  int c = threadIdx.x + blockIdx.x * blockDim.x;
  if (c >= C) return;
  float m = sum[c] * invcnt;
  float v = sq[c] * invcnt - m * m;
  float inv = rsqrtf(v + 1e-5f);
  float s = g[c] * inv;
  sc[c] = s;
  sh[c] = fmaf(-m, s, be[c]);
}

// ---------------- split-bf16 MFMA GEMM: Y = preact(A (+Add)) @ Wt^T + bias ------
// A fp32 [M,K]; Wt_hi/lo bf16 [N,K] pre-transposed; Y fp32. Near-fp32 precision via
// acc = A_hi*B_hi + A_hi*B_lo + A_lo*B_hi (fp32 MFMA accumulate).
// M%128==0, K%64==0, N%64==0. In-place (Y==A) safe when gridDim.y==1 (each block
// reads/writes only its own 128 rows, barrier-ordered).
__global__ __launch_bounds__(256) void mfma_gemm_kernel(
    const float* A, int lda,
    const float* __restrict__ Add, int ldadd,
    const float* __restrict__ preSc, const float* __restrict__ preSh,
    const unsigned short* __restrict__ Wt_hi, const unsigned short* __restrict__ Wt_lo,
    const float* __restrict__ bias,
    float* Y, int ldy,
    float* __restrict__ sum, float* __restrict__ sq,
    int M, int K, int N)
{
  __shared__ unsigned short AsH[128][72];  // 72 = 64 + 8 pad (keeps 16B align, 2-way banks)
  __shared__ unsigned short AsL[128][72];
  __shared__ unsigned short BsH[64][72];
  __shared__ unsigned short BsL[64][72];
  __shared__ float redY[64];
  __shared__ float redQ[64];
  int tid = threadIdx.x;
  int lane = tid & 63, wid = tid >> 6;
  int wr = wid >> 1, wc = wid & 1;
  int row0 = blockIdx.x * 128;
  int col0 = blockIdx.y * 64;
  int m16 = lane & 15, quad = lane >> 4;

  f32x4 acc[4][2];
#pragma unroll
  for (int i = 0; i < 4; ++i)
#pragma unroll
    for (int j = 0; j < 2; ++j) acc[i][j] = {0.f, 0.f, 0.f, 0.f};

  for (int k0 = 0; k0 < K; k0 += 64) {
    // stage A tile: fp32 load (+Add, +BN/ReLU) then hi/lo split
#pragma unroll
    for (int it = 0; it < 8; ++it) {
      int slot = tid + it * 256;
      int r = slot >> 4, cg = slot & 15;
      float4 v = *(const float4*)(A + (u64)(row0 + r) * lda + k0 + cg * 4);
      if (Add) {
        float4 a2 = *(const float4*)(Add + (u64)(row0 + r) * ldadd + k0 + cg * 4);
        v.x += a2.x; v.y += a2.y; v.z += a2.z; v.w += a2.w;
      }
      if (preSc) {
        float4 s4 = *(const float4*)(preSc + k0 + cg * 4);
        float4 h4 = *(const float4*)(preSh + k0 + cg * 4);
        v.x = fmaxf(fmaf(v.x, s4.x, h4.x), 0.f);
        v.y = fmaxf(fmaf(v.y, s4.y, h4.y), 0.f);
        v.z = fmaxf(fmaf(v.z, s4.z, h4.z), 0.f);
        v.w = fmaxf(fmaf(v.w, s4.w, h4.w), 0.f);
      }
      unsigned short hx = f2bf(v.x), hy = f2bf(v.y), hz = f2bf(v.z), hw = f2bf(v.w);
      unsigned short lx = f2bf(v.x - b2f(hx)), ly = f2bf(v.y - b2f(hy));
      unsigned short lz = f2bf(v.z - b2f(hz)), lw = f2bf(v.w - b2f(hw));
      uint2 ph, pl;
      ph.x = (unsigned)hx | ((unsigned)hy << 16);
      ph.y = (unsigned)hz | ((unsigned)hw << 16);
      pl.x = (unsigned)lx | ((unsigned)ly << 16);
      pl.y = (unsigned)lz | ((unsigned)lw << 16);
      *(uint2*)&AsH[r][cg * 4] = ph;
      *(uint2*)&AsL[r][cg * 4] = pl;
    }
    // stage B tile
#pragma unroll
    for (int it = 0; it < 2; ++it) {
      int slot = tid + it * 256;
      int n = slot >> 3, cg = slot & 7;
      u64 off = (u64)(col0 + n) * K + k0 + cg * 8;
      *(uint4*)&BsH[n][cg * 8] = *(const uint4*)(Wt_hi + off);
      *(uint4*)&BsL[n][cg * 8] = *(const uint4*)(Wt_lo + off);
    }
    __syncthreads();
#pragma unroll
    for (int ks = 0; ks < 64; ks += 32) {
      bf16x8 afh[4], afl[4], bfh[2], bfl[2];
#pragma unroll
      for (int rt = 0; rt < 4; ++rt) {
        afh[rt] = *(const bf16x8*)&AsH[wr * 64 + rt * 16 + m16][ks + quad * 8];
        afl[rt] = *(const bf16x8*)&AsL[wr * 64 + rt * 16 + m16][ks + quad * 8];
      }
#pragma unroll
      for (int ct = 0; ct < 2; ++ct) {
        bfh[ct] = *(const bf16x8*)&BsH[wc * 32 + ct * 16 + m16][ks + quad * 8];
        bfl[ct] = *(const bf16x8*)&BsL[wc * 32 + ct * 16 + m16][ks + quad * 8];
      }
#pragma unroll
      for (int rt = 0; rt < 4; ++rt)
#pragma unroll
        for (int ct = 0; ct < 2; ++ct) {
          acc[rt][ct] = __builtin_amdgcn_mfma_f32_16x16x32_bf16(afh[rt], bfh[ct], acc[rt][ct], 0, 0, 0);
          acc[rt][ct] = __builtin_amdgcn_mfma_f32_16x16x32_bf16(afh[rt], bfl[ct], acc[rt][ct], 0, 0, 0);
          acc[rt][ct] = __builtin_amdgcn_mfma_f32_16x16x32_bf16(afl[rt], bfh[ct], acc[rt][ct], 0, 0, 0);
        }
    }
    __syncthreads();
  }
  // epilogue: bias, store, stats
  if (sum) {
    if (tid < 64) { redY[tid] = 0.f; redQ[tid] = 0.f; }
    __syncthreads();
  }
#pragma unroll
  for (int ct = 0; ct < 2; ++ct) {
    int lcol = wc * 32 + ct * 16 + m16;
    int col = col0 + lcol;
    float bcol = bias[col];
    float cy = 0.f, cq = 0.f;
#pragma unroll
    for (int rt = 0; rt < 4; ++rt) {
#pragma unroll
      for (int rg = 0; rg < 4; ++rg) {
        int row = row0 + wr * 64 + rt * 16 + quad * 4 + rg;
        float v = acc[rt][ct][rg] + bcol;
        Y[(u64)row * ldy + col] = v;
        cy += v; cq += v * v;
      }
    }
    if (sum) {
      cy += __shfl_xor(cy, 16, 64); cy += __shfl_xor(cy, 32, 64);
      cq += __shfl_xor(cq, 16, 64); cq += __shfl_xor(cq, 32, 64);
      if (quad == 0) {
        atomicAdd(&redY[lcol], cy);
        atomicAdd(&redQ[lcol], cq);
      }
    }
  }
  if (sum) {
    __syncthreads();
    if (tid < 64) {
      atomicAdd(&sum[col0 + tid], redY[tid]);
      atomicAdd(&sq[col0 + tid], redQ[tid]);
    }
  }
}

// ---------------- fp32 tiled GEMM (head only, M=64) ----------------
template<int TM, int TN>
__global__ __launch_bounds__(256) void gemm_bn_kernel(
    const float* A, int lda,
    const float* __restrict__ Add, int ldadd,
    const float* __restrict__ preSc, const float* __restrict__ preSh,
    const float* __restrict__ W, const float* __restrict__ bias,
    float* Y, int ldy,
    float* __restrict__ sum, float* __restrict__ sq,
    int M, int K, int Cout)
{
  constexpr int BM = 16 * TM, BN = 16 * TN, BK = 16;
  __shared__ float As[BM * (BK + 1)];
  __shared__ float Ws[BK * (BN + 1)];
  __shared__ float red[16 * BN];
  int tid = threadIdx.x;
  int tx = tid & 15, ty = tid >> 4;
  int row0 = blockIdx.x * BM;
  int col0 = blockIdx.y * BN;
  float acc[TM][TN];
#pragma unroll
  for (int i = 0; i < TM; ++i)
#pragma unroll
    for (int j = 0; j < TN; ++j) acc[i][j] = 0.f;

  for (int k0 = 0; k0 < K; k0 += BK) {
    for (int idx = tid * 4; idx < BM * BK; idx += 1024) {
      int r = idx >> 4;
      int kk = idx & 15;
      int grow = row0 + r;
      float4 v = {0.f, 0.f, 0.f, 0.f};
      if (grow < M) {
        v = *(const float4*)(A + (u64)grow * lda + k0 + kk);
        if (preSc) {
          float4 s4 = *(const float4*)(preSc + k0 + kk);
          float4 h4 = *(const float4*)(preSh + k0 + kk);
          v.x = fmaxf(fmaf(v.x, s4.x, h4.x), 0.f);
          v.y = fmaxf(fmaf(v.y, s4.y, h4.y), 0.f);
          v.z = fmaxf(fmaf(v.z, s4.z, h4.z), 0.f);
          v.w = fmaxf(fmaf(v.w, s4.w, h4.w), 0.f);
        }
      }
      float* p = &As[r * (BK + 1) + kk];
      p[0] = v.x; p[1] = v.y; p[2] = v.z; p[3] = v.w;
    }
    for (int idx = tid * 4; idx < BK * BN; idx += 1024) {
      int kk = idx / BN;
      int cc = idx % BN;
      int gc = col0 + cc;
      float4 v = {0.f, 0.f, 0.f, 0.f};
      const float* wp = W + (u64)(k0 + kk) * Cout + gc;
      if (gc + 3 < Cout) v = *(const float4*)wp;
      else {
        if (gc + 0 < Cout) v.x = wp[0];
        if (gc + 1 < Cout) v.y = wp[1];
        if (gc + 2 < Cout) v.z = wp[2];
      }
      float* p = &Ws[kk * (BN + 1) + cc];
      p[0] = v.x; p[1] = v.y; p[2] = v.z; p[3] = v.w;
    }
    __syncthreads();
#pragma unroll
    for (int kk = 0; kk < BK; ++kk) {
      float a[TM], w[TN];
#pragma unroll
      for (int j = 0; j < TN; ++j) w[j] = Ws[kk * (BN + 1) + tx * TN + j];
#pragma unroll
      for (int i = 0; i < TM; ++i) a[i] = As[(ty * TM + i) * (BK + 1) + kk];
#pragma unroll
      for (int i = 0; i < TM; ++i)
#pragma unroll
        for (int j = 0; j < TN; ++j) acc[i][j] = fmaf(a[i], w[j], acc[i][j]);
    }
    __syncthreads();
  }
  float bl[TN];
  int cbase = col0 + tx * TN;
#pragma unroll
  for (int j = 0; j < TN; ++j) bl[j] = (cbase + j < Cout) ? bias[cbase + j] : 0.f;
  float csY[TN], csQ[TN];
#pragma unroll
  for (int j = 0; j < TN; ++j) { csY[j] = 0.f; csQ[j] = 0.f; }
#pragma unroll
  for (int i = 0; i < TM; ++i) {
    int grow = row0 + ty * TM + i;
    if (grow < M) {
#pragma unroll
      for (int j = 0; j < TN; ++j) {
        float v = acc[i][j] + bl[j];
        if (cbase + j < Cout) Y[(u64)grow * ldy + cbase + j] = v;
        csY[j] += v; csQ[j] += v * v;
      }
    }
  }
  if (sum) {
    __syncthreads();
#pragma unroll
    for (int j = 0; j < TN; ++j) red[ty * BN + tx * TN + j] = csY[j];
    __syncthreads();
    if (tid < BN) {
      float t = 0.f;
#pragma unroll
      for (int r = 0; r < 16; ++r) t += red[r * BN + tid];
      if (col0 + tid < Cout) atomicAdd(&sum[col0 + tid], t);
    }
    __syncthreads();
#pragma unroll
    for (int j = 0; j < TN; ++j) red[ty * BN + tx * TN + j] = csQ[j];
    __syncthreads();
    if (tid < BN) {
      float t = 0.f;
#pragma unroll
      for (int r = 0; r < 16; ++r) t += red[r * BN + tid];
      if (col0 + tid < Cout) atomicAdd(&sq[col0 + tid], t);
    }
  }
}

// ---------------- in-place act (bn+relu) + stats of result ----------------
__global__ __launch_bounds__(256) void act_stats_kernel(
    float* __restrict__ y, const float* __restrict__ sc, const float* __restrict__ sh,
    float* __restrict__ sum, float* __restrict__ sq, int total, int cmask)
{
  __shared__ float red[256];
  int tid = threadIdx.x;
  int c = tid & cmask;
  float s = sc[c], b = sh[c];
  float ls = 0.f, lq = 0.f;
  for (int idx = blockIdx.x * 256 + tid; idx < total; idx += gridDim.x * 256) {
    float v = fmaxf(fmaf(y[idx], s, b), 0.f);
    y[idx] = v;
    ls += v; lq += v * v;
  }
  red[tid] = ls; __syncthreads();
  if (tid <= cmask) {
    float t = 0.f;
    for (int k = tid; k < 256; k += cmask + 1) t += red[k];
    atomicAdd(&sum[tid], t);
  }
  __syncthreads();
  red[tid] = lq; __syncthreads();
  if (tid <= cmask) {
    float t = 0.f;
    for (int k = tid; k < 256; k += cmask + 1) t += red[k];
    atomicAdd(&sq[tid], t);
  }
}

// ---------------- apply outer BN into h slice ----------------
__global__ __launch_bounds__(256) void apply_bn_kernel(
    const float* __restrict__ a, const float* __restrict__ sc, const float* __restrict__ sh,
    float* __restrict__ h, int off, int cshift, int cmask, int total)
{
  for (int idx = blockIdx.x * 256 + threadIdx.x; idx < total; idx += gridDim.x * 256) {
    int r = idx >> cshift;
    int c = idx & cmask;
    h[(u64)r * 512 + off + c] = fmaf(a[idx], sc[c], sh[c]);
  }
}

// ---------------- EdgeConv segment_max (relu'd values >= 0 -> int atomicMax) ------
__global__ __launch_bounds__(256) void x0max_kernel(
    const float* __restrict__ y3, const float* __restrict__ sc, const float* __restrict__ sh,
    const int* __restrict__ dst, float* __restrict__ h)
{
  const u64 total = (u64)E_EDGES * 64;
  for (u64 idx = (u64)blockIdx.x * 256 + threadIdx.x; idx < total; idx += (u64)gridDim.x * 256) {
    int e = (int)(idx >> 6);
    int c = (int)(idx & 63);
    float v = fmaxf(fmaf(y3[idx], sc[c], sh[c]), 0.f);
    atomicMax((int*)(h + (u64)dst[e] * 512 + c), __float_as_int(v));
  }
}

// ---------------- GIN segment_sum scatter ----------------
__global__ __launch_bounds__(256) void scatter_add_kernel(
    const float* __restrict__ h, int off, int cshift, int cmask,
    const int* __restrict__ src, const int* __restrict__ dst,
    float* __restrict__ agg, u64 total)
{
  for (u64 idx = (u64)blockIdx.x * 256 + threadIdx.x; idx < total; idx += (u64)gridDim.x * 256) {
    int e = (int)(idx >> cshift);
    int c = (int)(idx & cmask);
    atomicAdd(agg + ((u64)dst[e] << cshift) + c, h[(u64)src[e] * 512 + off + c]);
  }
}

// ---------------- graph pooling ----------------
__global__ __launch_bounds__(256) void pool_kernel(
    const float* __restrict__ hl, const float* __restrict__ sc, const float* __restrict__ sh,
    float* __restrict__ o)
{
  int g = blockIdx.x;
  int c = blockIdx.y * 256 + threadIdx.x;
  float s = sc[c], b = sh[c];
  const float* p = hl + (u64)g * NPG * 1024 + c;
  float mx = 0.f, sm = 0.f;
  for (int n = 0; n < NPG; ++n) {
    float v = fmaxf(fmaf(p[(u64)n * 1024], s, b), 0.f);
    mx = fmaxf(mx, v);
    sm += v;
  }
  o[g * 2048 + c] = mx;
  o[g * 2048 + 1024 + c] = sm * (1.f / NPG);
}

// ---------------- log_softmax over 40 cols ----------------
__global__ void lsm_kernel(const float* __restrict__ logits, float* __restrict__ out)
{
  int r = blockIdx.x;
  int c = threadIdx.x;
  float v = (c < 40) ? logits[r * 40 + c] : -INFINITY;
  float m = v;
  for (int off = 32; off; off >>= 1) m = fmaxf(m, __shfl_xor(m, off, 64));
  float e = (c < 40) ? expf(v - m) : 0.f;
  float s = e;
  for (int off = 32; off; off >>= 1) s += __shfl_xor(s, off, 64);
  if (c < 40) out[r * 40 + c] = (v - m) - logf(s);
}

extern "C" void kernel_launch(void* const* d_in, const int* in_sizes, int n_in,
                              void* d_out, int out_size, void* d_ws, size_t ws_size,
                              hipStream_t stream)
{
  const float* x    = (const float*)d_in[0];
  const int*   ei   = (const int*)d_in[1];
  const int*   srcI = ei;
  const int*   dstI = ei + E_EDGES;
  const float* ecW1 = (const float*)d_in[3];
  const float* ecb1 = (const float*)d_in[4];
  const float* ecg1 = (const float*)d_in[5];
  const float* ecbe1= (const float*)d_in[6];
  const float* ecW2 = (const float*)d_in[7];
  const float* ecb2 = (const float*)d_in[8];
  const float* ecg2 = (const float*)d_in[9];
  const float* ecbe2= (const float*)d_in[10];
  const float* ecW3 = (const float*)d_in[11];
  const float* ecb3 = (const float*)d_in[12];
  const float* ecg3 = (const float*)d_in[13];
  const float* ecbe3= (const float*)d_in[14];
  const float* g1W  = (const float*)d_in[15];
  const float* g1b  = (const float*)d_in[16];
  const float* g1g  = (const float*)d_in[17];
  const float* g1be = (const float*)d_in[18];
  const float* g2W  = (const float*)d_in[19];
  const float* g2b  = (const float*)d_in[20];
  const float* g2g  = (const float*)d_in[21];
  const float* g2be = (const float*)d_in[22];
  const float* g3W  = (const float*)d_in[23];
  const float* g3b  = (const float*)d_in[24];
  const float* g3g  = (const float*)d_in[25];
  const float* g3be = (const float*)d_in[26];
  const float* bn1g = (const float*)d_in[27];
  const float* bn1be= (const float*)d_in[28];
  const float* bn2g = (const float*)d_in[29];
  const float* bn2be= (const float*)d_in[30];
  const float* bn3g = (const float*)d_in[31];
  const float* bn3be= (const float*)d_in[32];
  const float* linW = (const float*)d_in[33];
  const float* linb = (const float*)d_in[34];
  const float* ling = (const float*)d_in[35];
  const float* linbe= (const float*)d_in[36];
  const float* h1W  = (const float*)d_in[37];
  const float* h1b  = (const float*)d_in[38];
  const float* h1g  = (const float*)d_in[39];
  const float* h1be = (const float*)d_in[40];
  const float* h2W  = (const float*)d_in[41];
  const float* h2b  = (const float*)d_in[42];
  const float* h2g  = (const float*)d_in[43];
  const float* h2be = (const float*)d_in[44];
  const float* outW = (const float*)d_in[45];
  const float* outb = (const float*)d_in[46];

  char* ws = (char*)d_ws;
  const size_t MB = 1024ull * 1024ull;
  // ---- small area [0, 1 MiB) ----
  float* sum    = (float*)(ws);
  float* sq     = (float*)(ws + 4096);
  float* sc     = (float*)(ws + 8192);
  float* sh     = (float*)(ws + 12288);
  float* o_     = (float*)(ws + 16384);                           // [64,2048]
  float* yh1    = (float*)(ws + 16384 + 524288);                  // [64,512]
  float* yh2    = (float*)(ws + 16384 + 524288 + 131072);         // [64,256]
  float* logits = (float*)(ws + 16384 + 524288 + 131072 + 65536); // [64,40]
  // ---- transposed split-bf16 weights [1 MiB, 4 MiB) ----
  unsigned short* ec2WtH = (unsigned short*)(ws + 1 * MB);
  unsigned short* ec2WtL = (unsigned short*)(ws + 1 * MB + 8192);
  unsigned short* ec3WtH = (unsigned short*)(ws + 1 * MB + 16384);
  unsigned short* ec3WtL = (unsigned short*)(ws + 1 * MB + 24576);
  unsigned short* g1WtH  = (unsigned short*)(ws + 1 * MB + 32768);
  unsigned short* g1WtL  = (unsigned short*)(ws + 1 * MB + 40960);
  unsigned short* g2WtH  = (unsigned short*)(ws + 1 * MB + 49152);
  unsigned short* g2WtL  = (unsigned short*)(ws + 1 * MB + 65536);
  unsigned short* g3WtH  = (unsigned short*)(ws + 1 * MB + 81920);
  unsigned short* g3WtL  = (unsigned short*)(ws + 1 * MB + 147456);
  unsigned short* linWtH = (unsigned short*)(ws + 1 * MB + 212992);
  unsigned short* linWtL = (unsigned short*)(ws + 1 * MB + 212992 + 1048576);
  // ---- big region [4 MiB, 132 MiB): y fp32 [E,64] (128 MiB);
  //      then ytemp fp32 (32 MiB) + agg fp32 @ +32 MiB; then hl [N,1024] fp32 (128 MiB)
  float* y     = (float*)(ws + 4 * MB);
  float* ytemp = (float*)(ws + 4 * MB);
  float* agg   = (float*)(ws + 36 * MB);
  float* hl    = (float*)(ws + 4 * MB);
  // ---- h region [132 MiB, 196 MiB): [N,512] fp32 concat buffer ----
  float* h = (float*)(ws + 132 * MB);

#define ZZ(p, n) hipMemsetAsync((void*)(p), 0, (size_t)(n), stream)

  // ---------------- weight prep ----------------
  wt_kernel<<<16, 256, 0, stream>>>(ecW2, ec2WtH, ec2WtL, 6, 64, 4096);
  wt_kernel<<<16, 256, 0, stream>>>(ecW3, ec3WtH, ec3WtL, 6, 64, 4096);
  wt_kernel<<<16, 256, 0, stream>>>(g1W, g1WtH, g1WtL, 6, 64, 4096);
  wt_kernel<<<32, 256, 0, stream>>>(g2W, g2WtH, g2WtL, 6, 128, 8192);
  wt_kernel<<<128, 256, 0, stream>>>(g3W, g3WtH, g3WtL, 7, 256, 32768);
  wt_kernel<<<2048, 256, 0, stream>>>(linW, linWtH, linWtL, 9, 1024, 524288);

  // ---------------- EdgeConv (fp32 y, in-place) ----------------
  ZZ(sum, 8192);
  ec1_kernel<<<512, 256, 0, stream>>>(x, srcI, dstI, ecW1, ecb1, y, sum, sq);
  finstats_kernel<<<1, 1024, 0, stream>>>(sum, sq, 1.f / E_EDGES, ecg1, ecbe1, sc, sh, 64);
  ZZ(sum, 8192);
  mfma_gemm_kernel<<<dim3(E_EDGES / 128, 1), 256, 0, stream>>>(
      y, 64, nullptr, 0, sc, sh, ec2WtH, ec2WtL, ecb2, y, 64, sum, sq, E_EDGES, 64, 64);
  finstats_kernel<<<1, 1024, 0, stream>>>(sum, sq, 1.f / E_EDGES, ecg2, ecbe2, sc, sh, 64);
  ZZ(sum, 8192);
  mfma_gemm_kernel<<<dim3(E_EDGES / 128, 1), 256, 0, stream>>>(
      y, 64, nullptr, 0, sc, sh, ec3WtH, ec3WtL, ecb3, y, 64, sum, sq, E_EDGES, 64, 64);
  finstats_kernel<<<1, 1024, 0, stream>>>(sum, sq, 1.f / E_EDGES, ecg3, ecbe3, sc, sh, 64);
  ZZ(h, (size_t)N_NODES * 512 * 4);
  x0max_kernel<<<8192, 256, 0, stream>>>(y, sc, sh, dstI, h);

  // ---------------- GIN 1: x0(64)@off0 -> x1(64)@off64 ----------------
  ZZ(agg, (size_t)N_NODES * 64 * 4);
  scatter_add_kernel<<<8192, 256, 0, stream>>>(h, 0, 6, 63, srcI, dstI, agg, (u64)E_EDGES * 64);
  ZZ(sum, 8192);
  mfma_gemm_kernel<<<dim3(N_NODES / 128, 1), 256, 0, stream>>>(
      h, 512, agg, 64, nullptr, nullptr, g1WtH, g1WtL, g1b, ytemp, 64, sum, sq, N_NODES, 64, 64);
  finstats_kernel<<<1, 1024, 0, stream>>>(sum, sq, 1.f / N_NODES, g1g, g1be, sc, sh, 64);
  ZZ(sum, 8192);
  act_stats_kernel<<<512, 256, 0, stream>>>(ytemp, sc, sh, sum, sq, N_NODES * 64, 63);
  finstats_kernel<<<1, 1024, 0, stream>>>(sum, sq, 1.f / N_NODES, bn1g, bn1be, sc, sh, 64);
  apply_bn_kernel<<<1024, 256, 0, stream>>>(ytemp, sc, sh, h, 64, 6, 63, N_NODES * 64);

  // ---------------- GIN 2: x1(64)@off64 -> x2(128)@off128 ----------------
  ZZ(agg, (size_t)N_NODES * 64 * 4);
  scatter_add_kernel<<<8192, 256, 0, stream>>>(h, 64, 6, 63, srcI, dstI, agg, (u64)E_EDGES * 64);
  ZZ(sum, 8192);
  mfma_gemm_kernel<<<dim3(N_NODES / 128, 2), 256, 0, stream>>>(
      h + 64, 512, agg, 64, nullptr, nullptr, g2WtH, g2WtL, g2b, ytemp, 128, sum, sq, N_NODES, 64, 128);
  finstats_kernel<<<1, 1024, 0, stream>>>(sum, sq, 1.f / N_NODES, g2g, g2be, sc, sh, 128);
  ZZ(sum, 8192);
  act_stats_kernel<<<512, 256, 0, stream>>>(ytemp, sc, sh, sum, sq, N_NODES * 128, 127);
  finstats_kernel<<<1, 1024, 0, stream>>>(sum, sq, 1.f / N_NODES, bn2g, bn2be, sc, sh, 128);
  apply_bn_kernel<<<1024, 256, 0, stream>>>(ytemp, sc, sh, h, 128, 7, 127, N_NODES * 128);

  // ---------------- GIN 3: x2(128)@off128 -> x3(256)@off256 ----------------
  ZZ(agg, (size_t)N_NODES * 128 * 4);
  scatter_add_kernel<<<8192, 256, 0, stream>>>(h, 128, 7, 127, srcI, dstI, agg, (u64)E_EDGES * 128);
  ZZ(sum, 8192);
  mfma_gemm_kernel<<<dim3(N_NODES / 128, 4), 256, 0, stream>>>(
      h + 128, 512, agg, 128, nullptr, nullptr, g3WtH, g3WtL, g3b, ytemp, 256, sum, sq, N_NODES, 128, 256);
  finstats_kernel<<<1, 1024, 0, stream>>>(sum, sq, 1.f / N_NODES, g3g, g3be, sc, sh, 256);
  ZZ(sum, 8192);
  act_stats_kernel<<<512, 256, 0, stream>>>(ytemp, sc, sh, sum, sq, N_NODES * 256, 255);
  finstats_kernel<<<1, 1024, 0, stream>>>(sum, sq, 1.f / N_NODES, bn3g, bn3be, sc, sh, 256);
  apply_bn_kernel<<<1024, 256, 0, stream>>>(ytemp, sc, sh, h, 256, 8, 255, N_NODES * 256);

  // ---------------- lin: [N,512] @ [512,1024] + stats; pool ----------------
  ZZ(sum, 8192);
  mfma_gemm_kernel<<<dim3(N_NODES / 128, 16), 256, 0, stream>>>(
      h, 512, nullptr, 0, nullptr, nullptr, linWtH, linWtL, linb, hl, 1024, sum, sq, N_NODES, 512, 1024);
  finstats_kernel<<<1, 1024, 0, stream>>>(sum, sq, 1.f / N_NODES, ling, linbe, sc, sh, 1024);
  pool_kernel<<<dim3(64, 4), 256, 0, stream>>>(hl, sc, sh, o_);

  // ---------------- head (fp32, M=64) ----------------
  ZZ(sum, 8192);
  gemm_bn_kernel<4, 4><<<dim3(1, 8), 256, 0, stream>>>(
      o_, 2048, nullptr, 0, nullptr, nullptr, h1W, h1b, yh1, 512, sum, sq, 64, 2048, 512);
  finstats_kernel<<<1, 1024, 0, stream>>>(sum, sq, 1.f / 64, h1g, h1be, sc, sh, 512);
  ZZ(sum, 8192);
  gemm_bn_kernel<4, 4><<<dim3(1, 4), 256, 0, stream>>>(
      yh1, 512, nullptr, 0, sc, sh, h2W, h2b, yh2, 256, sum, sq, 64, 512, 256);
  finstats_kernel<<<1, 1024, 0, stream>>>(sum, sq, 1.f / 64, h2g, h2be, sc, sh, 256);
  gemm_bn_kernel<4, 4><<<dim3(1, 1), 256, 0, stream>>>(
      yh2, 256, nullptr, 0, sc, sh, outW, outb, logits, 40, nullptr, nullptr, 64, 256, 40);
  lsm_kernel<<<64, 64, 0, stream>>>(logits, (float*)d_out);
#undef ZZ
}

// Round 5
// 1760.218 us; speedup vs baseline: 1.2954x; 1.0656x over previous
//
#include <hip/hip_runtime.h>
#include <math.h>

#define E_EDGES 524288
#define N_NODES 32768
#define N_GRAPHS 64
#define NPG 512

typedef unsigned long long u64;
using bf16x8 = __attribute__((ext_vector_type(8))) short;
using f32x4  = __attribute__((ext_vector_type(4))) float;

__device__ __forceinline__ unsigned short f2bf(float f) {
  unsigned int u = __float_as_uint(f);
  u += 0x7FFFu + ((u >> 16) & 1u);
  return (unsigned short)(u >> 16);
}
__device__ __forceinline__ float b2f(unsigned short s) {
  return __uint_as_float(((unsigned int)s) << 16);
}

// ---------------- weight transpose + split-bf16 cast ----------------
// Wt_hi[n*K+k] + Wt_lo[n*K+k] ~= W[k*N+n] to ~2^-17 relative
__global__ __launch_bounds__(256) void wt_kernel(
    const float* __restrict__ W, unsigned short* __restrict__ Wt_hi,
    unsigned short* __restrict__ Wt_lo, int kshift, int N, int total)
{
  int idx = blockIdx.x * 256 + threadIdx.x;
  if (idx >= total) return;
  int n = idx >> kshift;
  int k = idx & ((1 << kshift) - 1);
  float w = W[(u64)k * N + n];
  unsigned short hi = f2bf(w);
  Wt_hi[idx] = hi;
  Wt_lo[idx] = f2bf(w - b2f(hi));
}

// ---------------- EdgeConv layer 1: gather + [E,8]@[8,64] + stats (fp32 out) ----
__global__ __launch_bounds__(256) void ec1_kernel(
    const float* __restrict__ x, const int* __restrict__ src, const int* __restrict__ dst,
    const float* __restrict__ W, const float* __restrict__ b,
    float* __restrict__ y, float* __restrict__ sum, float* __restrict__ sq)
{
  __shared__ float Ws[512];
  __shared__ float bs[64];
  __shared__ float red[256];
  int tid = threadIdx.x;
  for (int i = tid; i < 512; i += 256) Ws[i] = W[i];
  if (tid < 64) bs[tid] = b[tid];
  __syncthreads();
  int c = tid & 63;
  int eslot = tid >> 6;
  float ls = 0.f, lq = 0.f;
  int stride = gridDim.x * 4;
  for (int e = blockIdx.x * 4 + eslot; e < E_EDGES; e += stride) {
    int s = src[e], d = dst[e];
    float m[8];
#pragma unroll
    for (int k = 0; k < 4; ++k) {
      float xi = x[d * 4 + k];
      float xj = x[s * 4 + k];
      m[k] = xi; m[4 + k] = xj - xi;
    }
    float acc = bs[c];
#pragma unroll
    for (int k = 0; k < 8; ++k) acc = fmaf(m[k], Ws[k * 64 + c], acc);
    y[(u64)e * 64 + c] = acc;
    ls += acc; lq += acc * acc;
  }
  red[tid] = ls; __syncthreads();
  if (tid < 64) atomicAdd(&sum[tid], red[tid] + red[tid + 64] + red[tid + 128] + red[tid + 192]);
  __syncthreads();
  red[tid] = lq; __syncthreads();
  if (tid < 64) atomicAdd(&sq[tid], red[tid] + red[tid + 64] + red[tid + 128] + red[tid + 192]);
}

// ---------------- stats -> scale/shift ----------------
__global__ void finstats_kernel(const float* __restrict__ sum, const float* __restrict__ sq,
                                float invcnt, const float* __restrict__ g, const float* __restrict__ be,
                                float* __restrict__ sc, float* __restrict__ sh, int C)
{
  int c = threadIdx.x + blockIdx.x * blockDim.x;
  if (c >= C) return;
  float m = sum[c] * invcnt;
  float v = sq[c] * invcnt - m * m;
  float inv = rsqrtf(v + 1e-5f);
  float s = g[c] * inv;
  sc[c] = s;
  sh[c] = fmaf(-m, s, be[c]);
}

// ---------------- split-bf16 MFMA GEMM v2 (A direct global->VGPR; B-only LDS) ----
// Y = preact(A (+Add)) @ Wt^T + bias, fused BN stats.
// grid: x = N/64 (col blocks), y = M/128 (row blocks); 256 thr = 4 waves;
// wave w owns rows [row0+32w, row0+32w+32), all 64 cols of its col block.
// A fp32 [M,K]; Wt_hi/lo bf16 [N,K]; Y fp32. M%128==0, K%64==0, N%64==0.
// In-place (Y==A) safe when gridDim.x==1: each wave reads only its own 32 rows
// (single k-chunk path K=64) or reads all chunks before writing (K>64 waves
// finish all reads of their rows before the epilogue writes them).
__global__ __launch_bounds__(256) void mfma_gemm_kernel(
    const float* A, int lda,
    const float* __restrict__ Add, int ldadd,
    const float* __restrict__ preSc, const float* __restrict__ preSh,
    const unsigned short* __restrict__ Wt_hi, const unsigned short* __restrict__ Wt_lo,
    const float* __restrict__ bias,
    float* Y, int ldy,
    float* __restrict__ sum, float* __restrict__ sq,
    int M, int K, int N)
{
  __shared__ unsigned short BsH[64][72];   // 64 cols x 64 k, +8 pad
  __shared__ unsigned short BsL[64][72];
  __shared__ float redY[64];
  __shared__ float redQ[64];
  int tid = threadIdx.x;
  int lane = tid & 63, wid = tid >> 6;
  int row0 = blockIdx.y * 128 + wid * 32;
  int col0 = blockIdx.x * 64;
  int m16 = lane & 15, quad = lane >> 4;

  f32x4 acc[2][4];  // [rt][ct]
#pragma unroll
  for (int i = 0; i < 2; ++i)
#pragma unroll
    for (int j = 0; j < 4; ++j) acc[i][j] = {0.f, 0.f, 0.f, 0.f};

  for (int k0 = 0; k0 < K; k0 += 64) {
    // ---- stage B chunk to LDS (all waves cooperate) ----
    if (k0) __syncthreads();   // previous chunk's reads complete
#pragma unroll
    for (int it = 0; it < 2; ++it) {
      int slot = tid + it * 256;
      int n = slot >> 3, cg = slot & 7;
      u64 off = (u64)(col0 + n) * K + k0 + cg * 8;
      *(uint4*)&BsH[n][cg * 8] = *(const uint4*)(Wt_hi + off);
      *(uint4*)&BsL[n][cg * 8] = *(const uint4*)(Wt_lo + off);
    }
    __syncthreads();

    // ---- A fragments: direct global load + fuse + split, in registers ----
    bf16x8 ah[2][2], al[2][2];   // [rt][ks2]
#pragma unroll
    for (int rt = 0; rt < 2; ++rt) {
      int grow = row0 + rt * 16 + m16;
      const float* ap = A + (u64)grow * lda + k0 + quad * 8;
      const float* addp = Add ? (Add + (u64)grow * ldadd + k0 + quad * 8) : nullptr;
#pragma unroll
      for (int ks2 = 0; ks2 < 2; ++ks2) {
        float4 v0 = *(const float4*)(ap + ks2 * 32);
        float4 v1 = *(const float4*)(ap + ks2 * 32 + 4);
        if (Add) {
          float4 a0 = *(const float4*)(addp + ks2 * 32);
          float4 a1 = *(const float4*)(addp + ks2 * 32 + 4);
          v0.x += a0.x; v0.y += a0.y; v0.z += a0.z; v0.w += a0.w;
          v1.x += a1.x; v1.y += a1.y; v1.z += a1.z; v1.w += a1.w;
        }
        if (preSc) {
          const float* scp = preSc + k0 + quad * 8 + ks2 * 32;
          const float* shp = preSh + k0 + quad * 8 + ks2 * 32;
          float4 s0 = *(const float4*)scp, s1 = *(const float4*)(scp + 4);
          float4 h0 = *(const float4*)shp, h1 = *(const float4*)(shp + 4);
          v0.x = fmaxf(fmaf(v0.x, s0.x, h0.x), 0.f);
          v0.y = fmaxf(fmaf(v0.y, s0.y, h0.y), 0.f);
          v0.z = fmaxf(fmaf(v0.z, s0.z, h0.z), 0.f);
          v0.w = fmaxf(fmaf(v0.w, s0.w, h0.w), 0.f);
          v1.x = fmaxf(fmaf(v1.x, s1.x, h1.x), 0.f);
          v1.y = fmaxf(fmaf(v1.y, s1.y, h1.y), 0.f);
          v1.z = fmaxf(fmaf(v1.z, s1.z, h1.z), 0.f);
          v1.w = fmaxf(fmaf(v1.w, s1.w, h1.w), 0.f);
        }
        float f[8] = {v0.x, v0.y, v0.z, v0.w, v1.x, v1.y, v1.z, v1.w};
        bf16x8 th, tl;
#pragma unroll
        for (int j = 0; j < 8; ++j) {
          unsigned short hi = f2bf(f[j]);
          th[j] = (short)hi;
          tl[j] = (short)f2bf(f[j] - b2f(hi));
        }
        ah[rt][ks2] = th;
        al[rt][ks2] = tl;
      }
    }

    // ---- MFMA: B frags from LDS, 3-term split accumulate ----
#pragma unroll
    for (int ks2 = 0; ks2 < 2; ++ks2) {
#pragma unroll
      for (int ct = 0; ct < 4; ++ct) {
        bf16x8 bh = *(const bf16x8*)&BsH[ct * 16 + m16][ks2 * 32 + quad * 8];
        bf16x8 bl = *(const bf16x8*)&BsL[ct * 16 + m16][ks2 * 32 + quad * 8];
#pragma unroll
        for (int rt = 0; rt < 2; ++rt) {
          acc[rt][ct] = __builtin_amdgcn_mfma_f32_16x16x32_bf16(ah[rt][ks2], bh, acc[rt][ct], 0, 0, 0);
          acc[rt][ct] = __builtin_amdgcn_mfma_f32_16x16x32_bf16(ah[rt][ks2], bl, acc[rt][ct], 0, 0, 0);
          acc[rt][ct] = __builtin_amdgcn_mfma_f32_16x16x32_bf16(al[rt][ks2], bh, acc[rt][ct], 0, 0, 0);
        }
      }
    }
  }

  // ---- epilogue: bias, store, stats ----
  float cys[4], cqs[4];
#pragma unroll
  for (int ct = 0; ct < 4; ++ct) {
    int col = col0 + ct * 16 + m16;
    float bcol = bias[col];
    float cy = 0.f, cq = 0.f;
#pragma unroll
    for (int rt = 0; rt < 2; ++rt) {
#pragma unroll
      for (int rg = 0; rg < 4; ++rg) {
        int row = row0 + rt * 16 + quad * 4 + rg;
        float v = acc[rt][ct][rg] + bcol;
        Y[(u64)row * ldy + col] = v;
        cy += v; cq += v * v;
      }
    }
    cys[ct] = cy; cqs[ct] = cq;
  }
  if (sum) {
#pragma unroll
    for (int ct = 0; ct < 4; ++ct) {
      cys[ct] += __shfl_xor(cys[ct], 16, 64); cys[ct] += __shfl_xor(cys[ct], 32, 64);
      cqs[ct] += __shfl_xor(cqs[ct], 16, 64); cqs[ct] += __shfl_xor(cqs[ct], 32, 64);
    }
    __syncthreads();   // B LDS reads done everywhere; safe to use red arrays now
    if (tid < 64) { redY[tid] = 0.f; redQ[tid] = 0.f; }
    __syncthreads();
    if (quad == 0) {
#pragma unroll
      for (int ct = 0; ct < 4; ++ct) {
        atomicAdd(&redY[ct * 16 + m16], cys[ct]);
        atomicAdd(&redQ[ct * 16 + m16], cqs[ct]);
      }
    }
    __syncthreads();
    if (tid < 64) {
      atomicAdd(&sum[col0 + tid], redY[tid]);
      atomicAdd(&sq[col0 + tid], redQ[tid]);
    }
  }
}

// ---------------- fp32 tiled GEMM (head only, M=64) ----------------
template<int TM, int TN>
__global__ __launch_bounds__(256) void gemm_bn_kernel(
    const float* A, int lda,
    const float* __restrict__ Add, int ldadd,
    const float* __restrict__ preSc, const float* __restrict__ preSh,
    const float* __restrict__ W, const float* __restrict__ bias,
    float* Y, int ldy,
    float* __restrict__ sum, float* __restrict__ sq,
    int M, int K, int Cout)
{
  constexpr int BM = 16 * TM, BN = 16 * TN, BK = 16;
  __shared__ float As[BM * (BK + 1)];
  __shared__ float Ws[BK * (BN + 1)];
  __shared__ float red[16 * BN];
  int tid = threadIdx.x;
  int tx = tid & 15, ty = tid >> 4;
  int row0 = blockIdx.x * BM;
  int col0 = blockIdx.y * BN;
  float acc[TM][TN];
#pragma unroll
  for (int i = 0; i < TM; ++i)
#pragma unroll
    for (int j = 0; j < TN; ++j) acc[i][j] = 0.f;

  for (int k0 = 0; k0 < K; k0 += BK) {
    for (int idx = tid * 4; idx < BM * BK; idx += 1024) {
      int r = idx >> 4;
      int kk = idx & 15;
      int grow = row0 + r;
      float4 v = {0.f, 0.f, 0.f, 0.f};
      if (grow < M) {
        v = *(const float4*)(A + (u64)grow * lda + k0 + kk);
        if (preSc) {
          float4 s4 = *(const float4*)(preSc + k0 + kk);
          float4 h4 = *(const float4*)(preSh + k0 + kk);
          v.x = fmaxf(fmaf(v.x, s4.x, h4.x), 0.f);
          v.y = fmaxf(fmaf(v.y, s4.y, h4.y), 0.f);
          v.z = fmaxf(fmaf(v.z, s4.z, h4.z), 0.f);
          v.w = fmaxf(fmaf(v.w, s4.w, h4.w), 0.f);
        }
      }
      float* p = &As[r * (BK + 1) + kk];
      p[0] = v.x; p[1] = v.y; p[2] = v.z; p[3] = v.w;
    }
    for (int idx = tid * 4; idx < BK * BN; idx += 1024) {
      int kk = idx / BN;
      int cc = idx % BN;
      int gc = col0 + cc;
      float4 v = {0.f, 0.f, 0.f, 0.f};
      const float* wp = W + (u64)(k0 + kk) * Cout + gc;
      if (gc + 3 < Cout) v = *(const float4*)wp;
      else {
        if (gc + 0 < Cout) v.x = wp[0];
        if (gc + 1 < Cout) v.y = wp[1];
        if (gc + 2 < Cout) v.z = wp[2];
      }
      float* p = &Ws[kk * (BN + 1) + cc];
      p[0] = v.x; p[1] = v.y; p[2] = v.z; p[3] = v.w;
    }
    __syncthreads();
#pragma unroll
    for (int kk = 0; kk < BK; ++kk) {
      float a[TM], w[TN];
#pragma unroll
      for (int j = 0; j < TN; ++j) w[j] = Ws[kk * (BN + 1) + tx * TN + j];
#pragma unroll
      for (int i = 0; i < TM; ++i) a[i] = As[(ty * TM + i) * (BK + 1) + kk];
#pragma unroll
      for (int i = 0; i < TM; ++i)
#pragma unroll
        for (int j = 0; j < TN; ++j) acc[i][j] = fmaf(a[i], w[j], acc[i][j]);
    }
    __syncthreads();
  }
  float bl[TN];
  int cbase = col0 + tx * TN;
#pragma unroll
  for (int j = 0; j < TN; ++j) bl[j] = (cbase + j < Cout) ? bias[cbase + j] : 0.f;
  float csY[TN], csQ[TN];
#pragma unroll
  for (int j = 0; j < TN; ++j) { csY[j] = 0.f; csQ[j] = 0.f; }
#pragma unroll
  for (int i = 0; i < TM; ++i) {
    int grow = row0 + ty * TM + i;
    if (grow < M) {
#pragma unroll
      for (int j = 0; j < TN; ++j) {
        float v = acc[i][j] + bl[j];
        if (cbase + j < Cout) Y[(u64)grow * ldy + cbase + j] = v;
        csY[j] += v; csQ[j] += v * v;
      }
    }
  }
  if (sum) {
    __syncthreads();
#pragma unroll
    for (int j = 0; j < TN; ++j) red[ty * BN + tx * TN + j] = csY[j];
    __syncthreads();
    if (tid < BN) {
      float t = 0.f;
#pragma unroll
      for (int r = 0; r < 16; ++r) t += red[r * BN + tid];
      if (col0 + tid < Cout) atomicAdd(&sum[col0 + tid], t);
    }
    __syncthreads();
#pragma unroll
    for (int j = 0; j < TN; ++j) red[ty * BN + tx * TN + j] = csQ[j];
    __syncthreads();
    if (tid < BN) {
      float t = 0.f;
#pragma unroll
      for (int r = 0; r < 16; ++r) t += red[r * BN + tid];
      if (col0 + tid < Cout) atomicAdd(&sq[col0 + tid], t);
    }
  }
}

// ---------------- in-place act (bn+relu) + stats of result ----------------
__global__ __launch_bounds__(256) void act_stats_kernel(
    float* __restrict__ y, const float* __restrict__ sc, const float* __restrict__ sh,
    float* __restrict__ sum, float* __restrict__ sq, int total, int cmask)
{
  __shared__ float red[256];
  int tid = threadIdx.x;
  int c = tid & cmask;
  float s = sc[c], b = sh[c];
  float ls = 0.f, lq = 0.f;
  for (int idx = blockIdx.x * 256 + tid; idx < total; idx += gridDim.x * 256) {
    float v = fmaxf(fmaf(y[idx], s, b), 0.f);
    y[idx] = v;
    ls += v; lq += v * v;
  }
  red[tid] = ls; __syncthreads();
  if (tid <= cmask) {
    float t = 0.f;
    for (int k = tid; k < 256; k += cmask + 1) t += red[k];
    atomicAdd(&sum[tid], t);
  }
  __syncthreads();
  red[tid] = lq; __syncthreads();
  if (tid <= cmask) {
    float t = 0.f;
    for (int k = tid; k < 256; k += cmask + 1) t += red[k];
    atomicAdd(&sq[tid], t);
  }
}

// ---------------- apply outer BN into h slice ----------------
__global__ __launch_bounds__(256) void apply_bn_kernel(
    const float* __restrict__ a, const float* __restrict__ sc, const float* __restrict__ sh,
    float* __restrict__ h, int off, int cshift, int cmask, int total)
{
  for (int idx = blockIdx.x * 256 + threadIdx.x; idx < total; idx += gridDim.x * 256) {
    int r = idx >> cshift;
    int c = idx & cmask;
    h[(u64)r * 512 + off + c] = fmaf(a[idx], sc[c], sh[c]);
  }
}

// ---------------- EdgeConv segment_max (relu'd values >= 0 -> int atomicMax) ------
__global__ __launch_bounds__(256) void x0max_kernel(
    const float* __restrict__ y3, const float* __restrict__ sc, const float* __restrict__ sh,
    const int* __restrict__ dst, float* __restrict__ h)
{
  const u64 total = (u64)E_EDGES * 64;
  for (u64 idx = (u64)blockIdx.x * 256 + threadIdx.x; idx < total; idx += (u64)gridDim.x * 256) {
    int e = (int)(idx >> 6);
    int c = (int)(idx & 63);
    float v = fmaxf(fmaf(y3[idx], sc[c], sh[c]), 0.f);
    atomicMax((int*)(h + (u64)dst[e] * 512 + c), __float_as_int(v));
  }
}

// ---------------- GIN segment_sum scatter ----------------
__global__ __launch_bounds__(256) void scatter_add_kernel(
    const float* __restrict__ h, int off, int cshift, int cmask,
    const int* __restrict__ src, const int* __restrict__ dst,
    float* __restrict__ agg, u64 total)
{
  for (u64 idx = (u64)blockIdx.x * 256 + threadIdx.x; idx < total; idx += (u64)gridDim.x * 256) {
    int e = (int)(idx >> cshift);
    int c = (int)(idx & cmask);
    atomicAdd(agg + ((u64)dst[e] << cshift) + c, h[(u64)src[e] * 512 + off + c]);
  }
}

// ---------------- graph pooling ----------------
__global__ __launch_bounds__(256) void pool_kernel(
    const float* __restrict__ hl, const float* __restrict__ sc, const float* __restrict__ sh,
    float* __restrict__ o)
{
  int g = blockIdx.x;
  int c = blockIdx.y * 256 + threadIdx.x;
  float s = sc[c], b = sh[c];
  const float* p = hl + (u64)g * NPG * 1024 + c;
  float mx = 0.f, sm = 0.f;
  for (int n = 0; n < NPG; ++n) {
    float v = fmaxf(fmaf(p[(u64)n * 1024], s, b), 0.f);
    mx = fmaxf(mx, v);
    sm += v;
  }
  o[g * 2048 + c] = mx;
  o[g * 2048 + 1024 + c] = sm * (1.f / NPG);
}

// ---------------- log_softmax over 40 cols ----------------
__global__ void lsm_kernel(const float* __restrict__ logits, float* __restrict__ out)
{
  int r = blockIdx.x;
  int c = threadIdx.x;
  float v = (c < 40) ? logits[r * 40 + c] : -INFINITY;
  float m = v;
  for (int off = 32; off; off >>= 1) m = fmaxf(m, __shfl_xor(m, off, 64));
  float e = (c < 40) ? expf(v - m) : 0.f;
  float s = e;
  for (int off = 32; off; off >>= 1) s += __shfl_xor(s, off, 64);
  if (c < 40) out[r * 40 + c] = (v - m) - logf(s);
}

extern "C" void kernel_launch(void* const* d_in, const int* in_sizes, int n_in,
                              void* d_out, int out_size, void* d_ws, size_t ws_size,
                              hipStream_t stream)
{
  const float* x    = (const float*)d_in[0];
  const int*   ei   = (const int*)d_in[1];
  const int*   srcI = ei;
  const int*   dstI = ei + E_EDGES;
  const float* ecW1 = (const float*)d_in[3];
  const float* ecb1 = (const float*)d_in[4];
  const float* ecg1 = (const float*)d_in[5];
  const float* ecbe1= (const float*)d_in[6];
  const float* ecW2 = (const float*)d_in[7];
  const float* ecb2 = (const float*)d_in[8];
  const float* ecg2 = (const float*)d_in[9];
  const float* ecbe2= (const float*)d_in[10];
  const float* ecW3 = (const float*)d_in[11];
  const float* ecb3 = (const float*)d_in[12];
  const float* ecg3 = (const float*)d_in[13];
  const float* ecbe3= (const float*)d_in[14];
  const float* g1W  = (const float*)d_in[15];
  const float* g1b  = (const float*)d_in[16];
  const float* g1g  = (const float*)d_in[17];
  const float* g1be = (const float*)d_in[18];
  const float* g2W  = (const float*)d_in[19];
  const float* g2b  = (const float*)d_in[20];
  const float* g2g  = (const float*)d_in[21];
  const float* g2be = (const float*)d_in[22];
  const float* g3W  = (const float*)d_in[23];
  const float* g3b  = (const float*)d_in[24];
  const float* g3g  = (const float*)d_in[25];
  const float* g3be = (const float*)d_in[26];
  const float* bn1g = (const float*)d_in[27];
  const float* bn1be= (const float*)d_in[28];
  const float* bn2g = (const float*)d_in[29];
  const float* bn2be= (const float*)d_in[30];
  const float* bn3g = (const float*)d_in[31];
  const float* bn3be= (const float*)d_in[32];
  const float* linW = (const float*)d_in[33];
  const float* linb = (const float*)d_in[34];
  const float* ling = (const float*)d_in[35];
  const float* linbe= (const float*)d_in[36];
  const float* h1W  = (const float*)d_in[37];
  const float* h1b  = (const float*)d_in[38];
  const float* h1g  = (const float*)d_in[39];
  const float* h1be = (const float*)d_in[40];
  const float* h2W  = (const float*)d_in[41];
  const float* h2b  = (const float*)d_in[42];
  const float* h2g  = (const float*)d_in[43];
  const float* h2be = (const float*)d_in[44];
  const float* outW = (const float*)d_in[45];
  const float* outb = (const float*)d_in[46];

  char* ws = (char*)d_ws;
  const size_t MB = 1024ull * 1024ull;
  // ---- small area [0, 1 MiB) ----
  float* sum    = (float*)(ws);
  float* sq     = (float*)(ws + 4096);
  float* sc     = (float*)(ws + 8192);
  float* sh     = (float*)(ws + 12288);
  float* o_     = (float*)(ws + 16384);                           // [64,2048]
  float* yh1    = (float*)(ws + 16384 + 524288);                  // [64,512]
  float* yh2    = (float*)(ws + 16384 + 524288 + 131072);         // [64,256]
  float* logits = (float*)(ws + 16384 + 524288 + 131072 + 65536); // [64,40]
  // ---- transposed split-bf16 weights [1 MiB, 4 MiB) ----
  unsigned short* ec2WtH = (unsigned short*)(ws + 1 * MB);
  unsigned short* ec2WtL = (unsigned short*)(ws + 1 * MB + 8192);
  unsigned short* ec3WtH = (unsigned short*)(ws + 1 * MB + 16384);
  unsigned short* ec3WtL = (unsigned short*)(ws + 1 * MB + 24576);
  unsigned short* g1WtH  = (unsigned short*)(ws + 1 * MB + 32768);
  unsigned short* g1WtL  = (unsigned short*)(ws + 1 * MB + 40960);
  unsigned short* g2WtH  = (unsigned short*)(ws + 1 * MB + 49152);
  unsigned short* g2WtL  = (unsigned short*)(ws + 1 * MB + 65536);
  unsigned short* g3WtH  = (unsigned short*)(ws + 1 * MB + 81920);
  unsigned short* g3WtL  = (unsigned short*)(ws + 1 * MB + 147456);
  unsigned short* linWtH = (unsigned short*)(ws + 1 * MB + 212992);
  unsigned short* linWtL = (unsigned short*)(ws + 1 * MB + 212992 + 1048576);
  // ---- big region [4 MiB, 132 MiB): y fp32 [E,64] (128 MiB);
  //      then ytemp fp32 (32 MiB) + agg fp32 @ +32 MiB; then hl [N,1024] fp32 (128 MiB)
  float* y     = (float*)(ws + 4 * MB);
  float* ytemp = (float*)(ws + 4 * MB);
  float* agg   = (float*)(ws + 36 * MB);
  float* hl    = (float*)(ws + 4 * MB);
  // ---- h region [132 MiB, 196 MiB): [N,512] fp32 concat buffer ----
  float* h = (float*)(ws + 132 * MB);

#define ZZ(p, n) hipMemsetAsync((void*)(p), 0, (size_t)(n), stream)

  // ---------------- weight prep ----------------
  wt_kernel<<<16, 256, 0, stream>>>(ecW2, ec2WtH, ec2WtL, 6, 64, 4096);
  wt_kernel<<<16, 256, 0, stream>>>(ecW3, ec3WtH, ec3WtL, 6, 64, 4096);
  wt_kernel<<<16, 256, 0, stream>>>(g1W, g1WtH, g1WtL, 6, 64, 4096);
  wt_kernel<<<32, 256, 0, stream>>>(g2W, g2WtH, g2WtL, 6, 128, 8192);
  wt_kernel<<<128, 256, 0, stream>>>(g3W, g3WtH, g3WtL, 7, 256, 32768);
  wt_kernel<<<2048, 256, 0, stream>>>(linW, linWtH, linWtL, 9, 1024, 524288);

  // ---------------- EdgeConv (fp32 y, in-place) ----------------
  ZZ(sum, 8192);
  ec1_kernel<<<512, 256, 0, stream>>>(x, srcI, dstI, ecW1, ecb1, y, sum, sq);
  finstats_kernel<<<1, 1024, 0, stream>>>(sum, sq, 1.f / E_EDGES, ecg1, ecbe1, sc, sh, 64);
  ZZ(sum, 8192);
  mfma_gemm_kernel<<<dim3(1, E_EDGES / 128), 256, 0, stream>>>(
      y, 64, nullptr, 0, sc, sh, ec2WtH, ec2WtL, ecb2, y, 64, sum, sq, E_EDGES, 64, 64);
  finstats_kernel<<<1, 1024, 0, stream>>>(sum, sq, 1.f / E_EDGES, ecg2, ecbe2, sc, sh, 64);
  ZZ(sum, 8192);
  mfma_gemm_kernel<<<dim3(1, E_EDGES / 128), 256, 0, stream>>>(
      y, 64, nullptr, 0, sc, sh, ec3WtH, ec3WtL, ecb3, y, 64, sum, sq, E_EDGES, 64, 64);
  finstats_kernel<<<1, 1024, 0, stream>>>(sum, sq, 1.f / E_EDGES, ecg3, ecbe3, sc, sh, 64);
  ZZ(h, (size_t)N_NODES * 512 * 4);
  x0max_kernel<<<8192, 256, 0, stream>>>(y, sc, sh, dstI, h);

  // ---------------- GIN 1: x0(64)@off0 -> x1(64)@off64 ----------------
  ZZ(agg, (size_t)N_NODES * 64 * 4);
  scatter_add_kernel<<<8192, 256, 0, stream>>>(h, 0, 6, 63, srcI, dstI, agg, (u64)E_EDGES * 64);
  ZZ(sum, 8192);
  mfma_gemm_kernel<<<dim3(1, N_NODES / 128), 256, 0, stream>>>(
      h, 512, agg, 64, nullptr, nullptr, g1WtH, g1WtL, g1b, ytemp, 64, sum, sq, N_NODES, 64, 64);
  finstats_kernel<<<1, 1024, 0, stream>>>(sum, sq, 1.f / N_NODES, g1g, g1be, sc, sh, 64);
  ZZ(sum, 8192);
  act_stats_kernel<<<512, 256, 0, stream>>>(ytemp, sc, sh, sum, sq, N_NODES * 64, 63);
  finstats_kernel<<<1, 1024, 0, stream>>>(sum, sq, 1.f / N_NODES, bn1g, bn1be, sc, sh, 64);
  apply_bn_kernel<<<1024, 256, 0, stream>>>(ytemp, sc, sh, h, 64, 6, 63, N_NODES * 64);

  // ---------------- GIN 2: x1(64)@off64 -> x2(128)@off128 ----------------
  ZZ(agg, (size_t)N_NODES * 64 * 4);
  scatter_add_kernel<<<8192, 256, 0, stream>>>(h, 64, 6, 63, srcI, dstI, agg, (u64)E_EDGES * 64);
  ZZ(sum, 8192);
  mfma_gemm_kernel<<<dim3(2, N_NODES / 128), 256, 0, stream>>>(
      h + 64, 512, agg, 64, nullptr, nullptr, g2WtH, g2WtL, g2b, ytemp, 128, sum, sq, N_NODES, 64, 128);
  finstats_kernel<<<1, 1024, 0, stream>>>(sum, sq, 1.f / N_NODES, g2g, g2be, sc, sh, 128);
  ZZ(sum, 8192);
  act_stats_kernel<<<512, 256, 0, stream>>>(ytemp, sc, sh, sum, sq, N_NODES * 128, 127);
  finstats_kernel<<<1, 1024, 0, stream>>>(sum, sq, 1.f / N_NODES, bn2g, bn2be, sc, sh, 128);
  apply_bn_kernel<<<1024, 256, 0, stream>>>(ytemp, sc, sh, h, 128, 7, 127, N_NODES * 128);

  // ---------------- GIN 3: x2(128)@off128 -> x3(256)@off256 ----------------
  ZZ(agg, (size_t)N_NODES * 128 * 4);
  scatter_add_kernel<<<8192, 256, 0, stream>>>(h, 128, 7, 127, srcI, dstI, agg, (u64)E_EDGES * 128);
  ZZ(sum, 8192);
  mfma_gemm_kernel<<<dim3(4, N_NODES / 128), 256, 0, stream>>>(
      h + 128, 512, agg, 128, nullptr, nullptr, g3WtH, g3WtL, g3b, ytemp, 256, sum, sq, N_NODES, 128, 256);
  finstats_kernel<<<1, 1024, 0, stream>>>(sum, sq, 1.f / N_NODES, g3g, g3be, sc, sh, 256);
  ZZ(sum, 8192);
  act_stats_kernel<<<512, 256, 0, stream>>>(ytemp, sc, sh, sum, sq, N_NODES * 256, 255);
  finstats_kernel<<<1, 1024, 0, stream>>>(sum, sq, 1.f / N_NODES, bn3g, bn3be, sc, sh, 256);
  apply_bn_kernel<<<1024, 256, 0, stream>>>(ytemp, sc, sh, h, 256, 8, 255, N_NODES * 256);

  // ---------------- lin: [N,512] @ [512,1024] + stats; pool ----------------
  ZZ(sum, 8192);
  mfma_gemm_kernel<<<dim3(16, N_NODES / 128), 256, 0, stream>>>(
      h, 512, nullptr, 0, nullptr, nullptr, linWtH, linWtL, linb, hl, 1024, sum, sq, N_NODES, 512, 1024);
  finstats_kernel<<<1, 1024, 0, stream>>>(sum, sq, 1.f / N_NODES, ling, linbe, sc, sh, 1024);
  pool_kernel<<<dim3(64, 4), 256, 0, stream>>>(hl, sc, sh, o_);

  // ---------------- head (fp32, M=64) ----------------
  ZZ(sum, 8192);
  gemm_bn_kernel<4, 4><<<dim3(1, 8), 256, 0, stream>>>(
      o_, 2048, nullptr, 0, nullptr, nullptr, h1W, h1b, yh1, 512, sum, sq, 64, 2048, 512);
  finstats_kernel<<<1, 1024, 0, stream>>>(sum, sq, 1.f / 64, h1g, h1be, sc, sh, 512);
  ZZ(sum, 8192);
  gemm_bn_kernel<4, 4><<<dim3(1, 4), 256, 0, stream>>>(
      yh1, 512, nullptr, 0, sc, sh, h2W, h2b, yh2, 256, sum, sq, 64, 512, 256);
  finstats_kernel<<<1, 1024, 0, stream>>>(sum, sq, 1.f / 64, h2g, h2be, sc, sh, 256);
  gemm_bn_kernel<4, 4><<<dim3(1, 1), 256, 0, stream>>>(
      yh2, 256, nullptr, 0, sc, sh, outW, outb, logits, 40, nullptr, nullptr, 64, 256, 40);
  lsm_kernel<<<64, 64, 0, stream>>>(logits, (float*)d_out);
#undef ZZ
}

// Round 6
// 1449.340 us; speedup vs baseline: 1.5732x; 1.2145x over previous
//
#include <hip/hip_runtime.h>
#include <math.h>

#define E_EDGES 524288
#define N_NODES 32768
#define N_GRAPHS 64
#define NPG 512

typedef unsigned long long u64;
using bf16x8 = __attribute__((ext_vector_type(8))) short;
using f32x4  = __attribute__((ext_vector_type(4))) float;

__device__ __forceinline__ unsigned short f2bf(float f) {
  unsigned int u = __float_as_uint(f);
  u += 0x7FFFu + ((u >> 16) & 1u);
  return (unsigned short)(u >> 16);
}
__device__ __forceinline__ float b2f(unsigned short s) {
  return __uint_as_float(((unsigned int)s) << 16);
}

// ================= CSR build (dst-sorted edge permutation) =================
__global__ __launch_bounds__(256) void hist_kernel(
    const int* __restrict__ dst, int* __restrict__ cnt)
{
  int e = blockIdx.x * 256 + threadIdx.x;
  atomicAdd(&cnt[dst[e]], 1);
}

__global__ __launch_bounds__(1024) void scan_kernel(
    const int* __restrict__ cnt, int* __restrict__ row_ptr)
{
  __shared__ int s[1024];
  int t = threadIdx.x;
  int base = t * 32;
  int local[32];
  int acc = 0;
#pragma unroll
  for (int i = 0; i < 32; ++i) { local[i] = acc; acc += cnt[base + i]; }
  s[t] = acc;
  __syncthreads();
  for (int d = 1; d < 1024; d <<= 1) {
    int v = (t >= d) ? s[t - d] : 0;
    __syncthreads();
    s[t] += v;
    __syncthreads();
  }
  int off = t ? s[t - 1] : 0;
#pragma unroll
  for (int i = 0; i < 32; ++i) row_ptr[base + i] = off + local[i];
  if (t == 1023) row_ptr[32768] = off + acc;
}

__global__ __launch_bounds__(256) void copy_kernel(
    const int* __restrict__ a, int* __restrict__ b)
{
  int i = blockIdx.x * 256 + threadIdx.x;
  b[i] = a[i];
}

__global__ __launch_bounds__(256) void fill_kernel(
    const int* __restrict__ src, const int* __restrict__ dst,
    int* __restrict__ pos, int* __restrict__ ssrc, int* __restrict__ sdst)
{
  int e = blockIdx.x * 256 + threadIdx.x;
  int d = dst[e];
  int p = atomicAdd(&pos[d], 1);
  ssrc[p] = src[e];
  sdst[p] = d;
}

// ---------------- weight transpose + split-bf16 cast ----------------
__global__ __launch_bounds__(256) void wt_kernel(
    const float* __restrict__ W, unsigned short* __restrict__ Wt_hi,
    unsigned short* __restrict__ Wt_lo, int kshift, int N, int total)
{
  int idx = blockIdx.x * 256 + threadIdx.x;
  if (idx >= total) return;
  int n = idx >> kshift;
  int k = idx & ((1 << kshift) - 1);
  float w = W[(u64)k * N + n];
  unsigned short hi = f2bf(w);
  Wt_hi[idx] = hi;
  Wt_lo[idx] = f2bf(w - b2f(hi));
}

// ---------------- EdgeConv layer 1 (sorted edges): gather + [E,8]@[8,64] -------
__global__ __launch_bounds__(256) void ec1_kernel(
    const float* __restrict__ x, const int* __restrict__ src, const int* __restrict__ dst,
    const float* __restrict__ W, const float* __restrict__ b,
    float* __restrict__ y, float* __restrict__ sum, float* __restrict__ sq)
{
  __shared__ float Ws[512];
  __shared__ float bs[64];
  __shared__ float red[256];
  int tid = threadIdx.x;
  for (int i = tid; i < 512; i += 256) Ws[i] = W[i];
  if (tid < 64) bs[tid] = b[tid];
  __syncthreads();
  int c = tid & 63;
  int eslot = tid >> 6;
  float ls = 0.f, lq = 0.f;
  int stride = gridDim.x * 4;
  for (int e = blockIdx.x * 4 + eslot; e < E_EDGES; e += stride) {
    int s = src[e], d = dst[e];
    float m[8];
#pragma unroll
    for (int k = 0; k < 4; ++k) {
      float xi = x[d * 4 + k];
      float xj = x[s * 4 + k];
      m[k] = xi; m[4 + k] = xj - xi;
    }
    float acc = bs[c];
#pragma unroll
    for (int k = 0; k < 8; ++k) acc = fmaf(m[k], Ws[k * 64 + c], acc);
    y[(u64)e * 64 + c] = acc;
    ls += acc; lq += acc * acc;
  }
  red[tid] = ls; __syncthreads();
  if (tid < 64) atomicAdd(&sum[tid], red[tid] + red[tid + 64] + red[tid + 128] + red[tid + 192]);
  __syncthreads();
  red[tid] = lq; __syncthreads();
  if (tid < 64) atomicAdd(&sq[tid], red[tid] + red[tid + 64] + red[tid + 128] + red[tid + 192]);
}

// ---------------- stats -> scale/shift ----------------
__global__ void finstats_kernel(const float* __restrict__ sum, const float* __restrict__ sq,
                                float invcnt, const float* __restrict__ g, const float* __restrict__ be,
                                float* __restrict__ sc, float* __restrict__ sh, int C)
{
  int c = threadIdx.x + blockIdx.x * blockDim.x;
  if (c >= C) return;
  float m = sum[c] * invcnt;
  float v = sq[c] * invcnt - m * m;
  float inv = rsqrtf(v + 1e-5f);
  float s = g[c] * inv;
  sc[c] = s;
  sh[c] = fmaf(-m, s, be[c]);
}

// ---------------- split-bf16 MFMA GEMM v2 (A direct global->VGPR; B-only LDS) ----
__global__ __launch_bounds__(256) void mfma_gemm_kernel(
    const float* A, int lda,
    const float* __restrict__ Add, int ldadd,
    const float* __restrict__ preSc, const float* __restrict__ preSh,
    const unsigned short* __restrict__ Wt_hi, const unsigned short* __restrict__ Wt_lo,
    const float* __restrict__ bias,
    float* Y, int ldy,
    float* __restrict__ sum, float* __restrict__ sq,
    int M, int K, int N)
{
  __shared__ unsigned short BsH[64][72];
  __shared__ unsigned short BsL[64][72];
  __shared__ float redY[64];
  __shared__ float redQ[64];
  int tid = threadIdx.x;
  int lane = tid & 63, wid = tid >> 6;
  int row0 = blockIdx.y * 128 + wid * 32;
  int col0 = blockIdx.x * 64;
  int m16 = lane & 15, quad = lane >> 4;

  f32x4 acc[2][4];
#pragma unroll
  for (int i = 0; i < 2; ++i)
#pragma unroll
    for (int j = 0; j < 4; ++j) acc[i][j] = {0.f, 0.f, 0.f, 0.f};

  for (int k0 = 0; k0 < K; k0 += 64) {
    if (k0) __syncthreads();
#pragma unroll
    for (int it = 0; it < 2; ++it) {
      int slot = tid + it * 256;
      int n = slot >> 3, cg = slot & 7;
      u64 off = (u64)(col0 + n) * K + k0 + cg * 8;
      *(uint4*)&BsH[n][cg * 8] = *(const uint4*)(Wt_hi + off);
      *(uint4*)&BsL[n][cg * 8] = *(const uint4*)(Wt_lo + off);
    }
    __syncthreads();

    bf16x8 ah[2][2], al[2][2];
#pragma unroll
    for (int rt = 0; rt < 2; ++rt) {
      int grow = row0 + rt * 16 + m16;
      const float* ap = A + (u64)grow * lda + k0 + quad * 8;
      const float* addp = Add ? (Add + (u64)grow * ldadd + k0 + quad * 8) : nullptr;
#pragma unroll
      for (int ks2 = 0; ks2 < 2; ++ks2) {
        float4 v0 = *(const float4*)(ap + ks2 * 32);
        float4 v1 = *(const float4*)(ap + ks2 * 32 + 4);
        if (Add) {
          float4 a0 = *(const float4*)(addp + ks2 * 32);
          float4 a1 = *(const float4*)(addp + ks2 * 32 + 4);
          v0.x += a0.x; v0.y += a0.y; v0.z += a0.z; v0.w += a0.w;
          v1.x += a1.x; v1.y += a1.y; v1.z += a1.z; v1.w += a1.w;
        }
        if (preSc) {
          const float* scp = preSc + k0 + quad * 8 + ks2 * 32;
          const float* shp = preSh + k0 + quad * 8 + ks2 * 32;
          float4 s0 = *(const float4*)scp, s1 = *(const float4*)(scp + 4);
          float4 h0 = *(const float4*)shp, h1 = *(const float4*)(shp + 4);
          v0.x = fmaxf(fmaf(v0.x, s0.x, h0.x), 0.f);
          v0.y = fmaxf(fmaf(v0.y, s0.y, h0.y), 0.f);
          v0.z = fmaxf(fmaf(v0.z, s0.z, h0.z), 0.f);
          v0.w = fmaxf(fmaf(v0.w, s0.w, h0.w), 0.f);
          v1.x = fmaxf(fmaf(v1.x, s1.x, h1.x), 0.f);
          v1.y = fmaxf(fmaf(v1.y, s1.y, h1.y), 0.f);
          v1.z = fmaxf(fmaf(v1.z, s1.z, h1.z), 0.f);
          v1.w = fmaxf(fmaf(v1.w, s1.w, h1.w), 0.f);
        }
        float f[8] = {v0.x, v0.y, v0.z, v0.w, v1.x, v1.y, v1.z, v1.w};
        bf16x8 th, tl;
#pragma unroll
        for (int j = 0; j < 8; ++j) {
          unsigned short hi = f2bf(f[j]);
          th[j] = (short)hi;
          tl[j] = (short)f2bf(f[j] - b2f(hi));
        }
        ah[rt][ks2] = th;
        al[rt][ks2] = tl;
      }
    }

#pragma unroll
    for (int ks2 = 0; ks2 < 2; ++ks2) {
#pragma unroll
      for (int ct = 0; ct < 4; ++ct) {
        bf16x8 bh = *(const bf16x8*)&BsH[ct * 16 + m16][ks2 * 32 + quad * 8];
        bf16x8 bl = *(const bf16x8*)&BsL[ct * 16 + m16][ks2 * 32 + quad * 8];
#pragma unroll
        for (int rt = 0; rt < 2; ++rt) {
          acc[rt][ct] = __builtin_amdgcn_mfma_f32_16x16x32_bf16(ah[rt][ks2], bh, acc[rt][ct], 0, 0, 0);
          acc[rt][ct] = __builtin_amdgcn_mfma_f32_16x16x32_bf16(ah[rt][ks2], bl, acc[rt][ct], 0, 0, 0);
          acc[rt][ct] = __builtin_amdgcn_mfma_f32_16x16x32_bf16(al[rt][ks2], bh, acc[rt][ct], 0, 0, 0);
        }
      }
    }
  }

  float cys[4], cqs[4];
#pragma unroll
  for (int ct = 0; ct < 4; ++ct) {
    int col = col0 + ct * 16 + m16;
    float bcol = bias[col];
    float cy = 0.f, cq = 0.f;
#pragma unroll
    for (int rt = 0; rt < 2; ++rt) {
#pragma unroll
      for (int rg = 0; rg < 4; ++rg) {
        int row = row0 + rt * 16 + quad * 4 + rg;
        float v = acc[rt][ct][rg] + bcol;
        Y[(u64)row * ldy + col] = v;
        cy += v; cq += v * v;
      }
    }
    cys[ct] = cy; cqs[ct] = cq;
  }
  if (sum) {
#pragma unroll
    for (int ct = 0; ct < 4; ++ct) {
      cys[ct] += __shfl_xor(cys[ct], 16, 64); cys[ct] += __shfl_xor(cys[ct], 32, 64);
      cqs[ct] += __shfl_xor(cqs[ct], 16, 64); cqs[ct] += __shfl_xor(cqs[ct], 32, 64);
    }
    __syncthreads();
    if (tid < 64) { redY[tid] = 0.f; redQ[tid] = 0.f; }
    __syncthreads();
    if (quad == 0) {
#pragma unroll
      for (int ct = 0; ct < 4; ++ct) {
        atomicAdd(&redY[ct * 16 + m16], cys[ct]);
        atomicAdd(&redQ[ct * 16 + m16], cqs[ct]);
      }
    }
    __syncthreads();
    if (tid < 64) {
      atomicAdd(&sum[col0 + tid], redY[tid]);
      atomicAdd(&sq[col0 + tid], redQ[tid]);
    }
  }
}

// ---------------- fp32 tiled GEMM (head only, M=64) ----------------
template<int TM, int TN>
__global__ __launch_bounds__(256) void gemm_bn_kernel(
    const float* A, int lda,
    const float* __restrict__ Add, int ldadd,
    const float* __restrict__ preSc, const float* __restrict__ preSh,
    const float* __restrict__ W, const float* __restrict__ bias,
    float* Y, int ldy,
    float* __restrict__ sum, float* __restrict__ sq,
    int M, int K, int Cout)
{
  constexpr int BM = 16 * TM, BN = 16 * TN, BK = 16;
  __shared__ float As[BM * (BK + 1)];
  __shared__ float Ws[BK * (BN + 1)];
  __shared__ float red[16 * BN];
  int tid = threadIdx.x;
  int tx = tid & 15, ty = tid >> 4;
  int row0 = blockIdx.x * BM;
  int col0 = blockIdx.y * BN;
  float acc[TM][TN];
#pragma unroll
  for (int i = 0; i < TM; ++i)
#pragma unroll
    for (int j = 0; j < TN; ++j) acc[i][j] = 0.f;

  for (int k0 = 0; k0 < K; k0 += BK) {
    for (int idx = tid * 4; idx < BM * BK; idx += 1024) {
      int r = idx >> 4;
      int kk = idx & 15;
      int grow = row0 + r;
      float4 v = {0.f, 0.f, 0.f, 0.f};
      if (grow < M) {
        v = *(const float4*)(A + (u64)grow * lda + k0 + kk);
        if (preSc) {
          float4 s4 = *(const float4*)(preSc + k0 + kk);
          float4 h4 = *(const float4*)(preSh + k0 + kk);
          v.x = fmaxf(fmaf(v.x, s4.x, h4.x), 0.f);
          v.y = fmaxf(fmaf(v.y, s4.y, h4.y), 0.f);
          v.z = fmaxf(fmaf(v.z, s4.z, h4.z), 0.f);
          v.w = fmaxf(fmaf(v.w, s4.w, h4.w), 0.f);
        }
      }
      float* p = &As[r * (BK + 1) + kk];
      p[0] = v.x; p[1] = v.y; p[2] = v.z; p[3] = v.w;
    }
    for (int idx = tid * 4; idx < BK * BN; idx += 1024) {
      int kk = idx / BN;
      int cc = idx % BN;
      int gc = col0 + cc;
      float4 v = {0.f, 0.f, 0.f, 0.f};
      const float* wp = W + (u64)(k0 + kk) * Cout + gc;
      if (gc + 3 < Cout) v = *(const float4*)wp;
      else {
        if (gc + 0 < Cout) v.x = wp[0];
        if (gc + 1 < Cout) v.y = wp[1];
        if (gc + 2 < Cout) v.z = wp[2];
      }
      float* p = &Ws[kk * (BN + 1) + cc];
      p[0] = v.x; p[1] = v.y; p[2] = v.z; p[3] = v.w;
    }
    __syncthreads();
#pragma unroll
    for (int kk = 0; kk < BK; ++kk) {
      float a[TM], w[TN];
#pragma unroll
      for (int j = 0; j < TN; ++j) w[j] = Ws[kk * (BN + 1) + tx * TN + j];
#pragma unroll
      for (int i = 0; i < TM; ++i) a[i] = As[(ty * TM + i) * (BK + 1) + kk];
#pragma unroll
      for (int i = 0; i < TM; ++i)
#pragma unroll
        for (int j = 0; j < TN; ++j) acc[i][j] = fmaf(a[i], w[j], acc[i][j]);
    }
    __syncthreads();
  }
  float bl[TN];
  int cbase = col0 + tx * TN;
#pragma unroll
  for (int j = 0; j < TN; ++j) bl[j] = (cbase + j < Cout) ? bias[cbase + j] : 0.f;
  float csY[TN], csQ[TN];
#pragma unroll
  for (int j = 0; j < TN; ++j) { csY[j] = 0.f; csQ[j] = 0.f; }
#pragma unroll
  for (int i = 0; i < TM; ++i) {
    int grow = row0 + ty * TM + i;
    if (grow < M) {
#pragma unroll
      for (int j = 0; j < TN; ++j) {
        float v = acc[i][j] + bl[j];
        if (cbase + j < Cout) Y[(u64)grow * ldy + cbase + j] = v;
        csY[j] += v; csQ[j] += v * v;
      }
    }
  }
  if (sum) {
    __syncthreads();
#pragma unroll
    for (int j = 0; j < TN; ++j) red[ty * BN + tx * TN + j] = csY[j];
    __syncthreads();
    if (tid < BN) {
      float t = 0.f;
#pragma unroll
      for (int r = 0; r < 16; ++r) t += red[r * BN + tid];
      if (col0 + tid < Cout) atomicAdd(&sum[col0 + tid], t);
    }
    __syncthreads();
#pragma unroll
    for (int j = 0; j < TN; ++j) red[ty * BN + tx * TN + j] = csQ[j];
    __syncthreads();
    if (tid < BN) {
      float t = 0.f;
#pragma unroll
      for (int r = 0; r < 16; ++r) t += red[r * BN + tid];
      if (col0 + tid < Cout) atomicAdd(&sq[col0 + tid], t);
    }
  }
}

// ---------------- in-place act (bn+relu) + stats of result ----------------
__global__ __launch_bounds__(256) void act_stats_kernel(
    float* __restrict__ y, const float* __restrict__ sc, const float* __restrict__ sh,
    float* __restrict__ sum, float* __restrict__ sq, int total, int cmask)
{
  __shared__ float red[256];
  int tid = threadIdx.x;
  int c = tid & cmask;
  float s = sc[c], b = sh[c];
  float ls = 0.f, lq = 0.f;
  for (int idx = blockIdx.x * 256 + tid; idx < total; idx += gridDim.x * 256) {
    float v = fmaxf(fmaf(y[idx], s, b), 0.f);
    y[idx] = v;
    ls += v; lq += v * v;
  }
  red[tid] = ls; __syncthreads();
  if (tid <= cmask) {
    float t = 0.f;
    for (int k = tid; k < 256; k += cmask + 1) t += red[k];
    atomicAdd(&sum[tid], t);
  }
  __syncthreads();
  red[tid] = lq; __syncthreads();
  if (tid <= cmask) {
    float t = 0.f;
    for (int k = tid; k < 256; k += cmask + 1) t += red[k];
    atomicAdd(&sq[tid], t);
  }
}

// ---------------- apply outer BN into h slice ----------------
__global__ __launch_bounds__(256) void apply_bn_kernel(
    const float* __restrict__ a, const float* __restrict__ sc, const float* __restrict__ sh,
    float* __restrict__ h, int off, int cshift, int cmask, int total)
{
  for (int idx = blockIdx.x * 256 + threadIdx.x; idx < total; idx += gridDim.x * 256) {
    int r = idx >> cshift;
    int c = idx & cmask;
    h[(u64)r * 512 + off + c] = fmaf(a[idx], sc[c], sh[c]);
  }
}

// ------------- EdgeConv segment_max via CSR (y is dst-sorted): wave per node ----
__global__ __launch_bounds__(256) void x0max_csr_kernel(
    const float* __restrict__ y3, const float* __restrict__ sc, const float* __restrict__ sh,
    const int* __restrict__ row_ptr, float* __restrict__ h)
{
  int n = blockIdx.x * 4 + (threadIdx.x >> 6);
  int lane = threadIdx.x & 63;
  int b = row_ptr[n], e = row_ptr[n + 1];
  float s = sc[lane], bb = sh[lane];
  float mx = 0.f;
  for (int i = b; i < e; ++i) {
    float v = fmaxf(fmaf(y3[(u64)i * 64 + lane], s, bb), 0.f);
    mx = fmaxf(mx, v);
  }
  h[(u64)n * 512 + lane] = mx;
}

// ------------- GIN neighbor-sum via CSR gather: wave per node, no atomics -------
template<int COLS>
__global__ __launch_bounds__(256) void gather_add_kernel(
    const float* __restrict__ h, int off,
    const int* __restrict__ row_ptr, const int* __restrict__ ssrc,
    float* __restrict__ agg)
{
  int n = blockIdx.x * 4 + (threadIdx.x >> 6);
  int lane = threadIdx.x & 63;
  int b = row_ptr[n], e = row_ptr[n + 1];
  float a0 = 0.f, a1 = 0.f;
  for (int i = b; i < e; ++i) {
    const float* p = h + (u64)ssrc[i] * 512 + off + lane;
    a0 += p[0];
    if (COLS > 64) a1 += p[64];
  }
  float* q = agg + (u64)n * COLS + lane;
  q[0] = a0;
  if (COLS > 64) q[64] = a1;
}

// ---------------- graph pooling ----------------
__global__ __launch_bounds__(256) void pool_kernel(
    const float* __restrict__ hl, const float* __restrict__ sc, const float* __restrict__ sh,
    float* __restrict__ o)
{
  int g = blockIdx.x;
  int c = blockIdx.y * 256 + threadIdx.x;
  float s = sc[c], b = sh[c];
  const float* p = hl + (u64)g * NPG * 1024 + c;
  float mx = 0.f, sm = 0.f;
  for (int n = 0; n < NPG; ++n) {
    float v = fmaxf(fmaf(p[(u64)n * 1024], s, b), 0.f);
    mx = fmaxf(mx, v);
    sm += v;
  }
  o[g * 2048 + c] = mx;
  o[g * 2048 + 1024 + c] = sm * (1.f / NPG);
}

// ---------------- log_softmax over 40 cols ----------------
__global__ void lsm_kernel(const float* __restrict__ logits, float* __restrict__ out)
{
  int r = blockIdx.x;
  int c = threadIdx.x;
  float v = (c < 40) ? logits[r * 40 + c] : -INFINITY;
  float m = v;
  for (int off = 32; off; off >>= 1) m = fmaxf(m, __shfl_xor(m, off, 64));
  float e = (c < 40) ? expf(v - m) : 0.f;
  float s = e;
  for (int off = 32; off; off >>= 1) s += __shfl_xor(s, off, 64);
  if (c < 40) out[r * 40 + c] = (v - m) - logf(s);
}

extern "C" void kernel_launch(void* const* d_in, const int* in_sizes, int n_in,
                              void* d_out, int out_size, void* d_ws, size_t ws_size,
                              hipStream_t stream)
{
  const float* x    = (const float*)d_in[0];
  const int*   ei   = (const int*)d_in[1];
  const int*   srcI = ei;
  const int*   dstI = ei + E_EDGES;
  const float* ecW1 = (const float*)d_in[3];
  const float* ecb1 = (const float*)d_in[4];
  const float* ecg1 = (const float*)d_in[5];
  const float* ecbe1= (const float*)d_in[6];
  const float* ecW2 = (const float*)d_in[7];
  const float* ecb2 = (const float*)d_in[8];
  const float* ecg2 = (const float*)d_in[9];
  const float* ecbe2= (const float*)d_in[10];
  const float* ecW3 = (const float*)d_in[11];
  const float* ecb3 = (const float*)d_in[12];
  const float* ecg3 = (const float*)d_in[13];
  const float* ecbe3= (const float*)d_in[14];
  const float* g1W  = (const float*)d_in[15];
  const float* g1b  = (const float*)d_in[16];
  const float* g1g  = (const float*)d_in[17];
  const float* g1be = (const float*)d_in[18];
  const float* g2W  = (const float*)d_in[19];
  const float* g2b  = (const float*)d_in[20];
  const float* g2g  = (const float*)d_in[21];
  const float* g2be = (const float*)d_in[22];
  const float* g3W  = (const float*)d_in[23];
  const float* g3b  = (const float*)d_in[24];
  const float* g3g  = (const float*)d_in[25];
  const float* g3be = (const float*)d_in[26];
  const float* bn1g = (const float*)d_in[27];
  const float* bn1be= (const float*)d_in[28];
  const float* bn2g = (const float*)d_in[29];
  const float* bn2be= (const float*)d_in[30];
  const float* bn3g = (const float*)d_in[31];
  const float* bn3be= (const float*)d_in[32];
  const float* linW = (const float*)d_in[33];
  const float* linb = (const float*)d_in[34];
  const float* ling = (const float*)d_in[35];
  const float* linbe= (const float*)d_in[36];
  const float* h1W  = (const float*)d_in[37];
  const float* h1b  = (const float*)d_in[38];
  const float* h1g  = (const float*)d_in[39];
  const float* h1be = (const float*)d_in[40];
  const float* h2W  = (const float*)d_in[41];
  const float* h2b  = (const float*)d_in[42];
  const float* h2g  = (const float*)d_in[43];
  const float* h2be = (const float*)d_in[44];
  const float* outW = (const float*)d_in[45];
  const float* outb = (const float*)d_in[46];

  char* ws = (char*)d_ws;
  const size_t MB = 1024ull * 1024ull;
  // ---- small area [0, 1 MiB) ----
  float* sum    = (float*)(ws);
  float* sq     = (float*)(ws + 4096);
  float* sc     = (float*)(ws + 8192);
  float* sh     = (float*)(ws + 12288);
  float* o_     = (float*)(ws + 16384);                           // [64,2048]
  float* yh1    = (float*)(ws + 16384 + 524288);                  // [64,512]
  float* yh2    = (float*)(ws + 16384 + 524288 + 131072);         // [64,256]
  float* logits = (float*)(ws + 16384 + 524288 + 131072 + 65536); // [64,40]
  // ---- transposed split-bf16 weights [1 MiB, 4 MiB) ----
  unsigned short* ec2WtH = (unsigned short*)(ws + 1 * MB);
  unsigned short* ec2WtL = (unsigned short*)(ws + 1 * MB + 8192);
  unsigned short* ec3WtH = (unsigned short*)(ws + 1 * MB + 16384);
  unsigned short* ec3WtL = (unsigned short*)(ws + 1 * MB + 24576);
  unsigned short* g1WtH  = (unsigned short*)(ws + 1 * MB + 32768);
  unsigned short* g1WtL  = (unsigned short*)(ws + 1 * MB + 40960);
  unsigned short* g2WtH  = (unsigned short*)(ws + 1 * MB + 49152);
  unsigned short* g2WtL  = (unsigned short*)(ws + 1 * MB + 65536);
  unsigned short* g3WtH  = (unsigned short*)(ws + 1 * MB + 81920);
  unsigned short* g3WtL  = (unsigned short*)(ws + 1 * MB + 147456);
  unsigned short* linWtH = (unsigned short*)(ws + 1 * MB + 212992);
  unsigned short* linWtL = (unsigned short*)(ws + 1 * MB + 212992 + 1048576);
  // ---- big region [4 MiB, 132 MiB): y fp32 [E,64] (128 MiB);
  //      then ytemp fp32 (32 MiB) + agg fp32 @ +32 MiB; then hl [N,1024] fp32 (128 MiB)
  float* y     = (float*)(ws + 4 * MB);
  float* ytemp = (float*)(ws + 4 * MB);
  float* agg   = (float*)(ws + 36 * MB);
  float* hl    = (float*)(ws + 4 * MB);
  // ---- h region [132 MiB, 196 MiB): [N,512] fp32 concat buffer ----
  float* h = (float*)(ws + 132 * MB);
  // ---- CSR region [196 MiB, 201 MiB) ----
  int* row_ptr = (int*)(ws + 196 * MB);             // 32769 ints
  int* cnt     = (int*)(ws + 196 * MB + 140000);    // 32768 ints (deg, then pos)
  int* ssrc    = (int*)(ws + 197 * MB);             // E ints (2 MiB)
  int* sdst    = (int*)(ws + 199 * MB);             // E ints (2 MiB)

#define ZZ(p, n) hipMemsetAsync((void*)(p), 0, (size_t)(n), stream)

  // ---------------- CSR build (edges sorted by dst) ----------------
  ZZ(cnt, 32768 * 4);
  hist_kernel<<<2048, 256, 0, stream>>>(dstI, cnt);
  scan_kernel<<<1, 1024, 0, stream>>>(cnt, row_ptr);
  copy_kernel<<<128, 256, 0, stream>>>(row_ptr, cnt);   // cnt := running positions
  fill_kernel<<<2048, 256, 0, stream>>>(srcI, dstI, cnt, ssrc, sdst);

  // ---------------- weight prep ----------------
  wt_kernel<<<16, 256, 0, stream>>>(ecW2, ec2WtH, ec2WtL, 6, 64, 4096);
  wt_kernel<<<16, 256, 0, stream>>>(ecW3, ec3WtH, ec3WtL, 6, 64, 4096);
  wt_kernel<<<16, 256, 0, stream>>>(g1W, g1WtH, g1WtL, 6, 64, 4096);
  wt_kernel<<<32, 256, 0, stream>>>(g2W, g2WtH, g2WtL, 6, 128, 8192);
  wt_kernel<<<128, 256, 0, stream>>>(g3W, g3WtH, g3WtL, 7, 256, 32768);
  wt_kernel<<<2048, 256, 0, stream>>>(linW, linWtH, linWtL, 9, 1024, 524288);

  // ---------------- EdgeConv (fp32 y, dst-sorted rows, in-place GEMMs) ---------
  ZZ(sum, 8192);
  ec1_kernel<<<512, 256, 0, stream>>>(x, ssrc, sdst, ecW1, ecb1, y, sum, sq);
  finstats_kernel<<<1, 1024, 0, stream>>>(sum, sq, 1.f / E_EDGES, ecg1, ecbe1, sc, sh, 64);
  ZZ(sum, 8192);
  mfma_gemm_kernel<<<dim3(1, E_EDGES / 128), 256, 0, stream>>>(
      y, 64, nullptr, 0, sc, sh, ec2WtH, ec2WtL, ecb2, y, 64, sum, sq, E_EDGES, 64, 64);
  finstats_kernel<<<1, 1024, 0, stream>>>(sum, sq, 1.f / E_EDGES, ecg2, ecbe2, sc, sh, 64);
  ZZ(sum, 8192);
  mfma_gemm_kernel<<<dim3(1, E_EDGES / 128), 256, 0, stream>>>(
      y, 64, nullptr, 0, sc, sh, ec3WtH, ec3WtL, ecb3, y, 64, sum, sq, E_EDGES, 64, 64);
  finstats_kernel<<<1, 1024, 0, stream>>>(sum, sq, 1.f / E_EDGES, ecg3, ecbe3, sc, sh, 64);
  x0max_csr_kernel<<<N_NODES / 4, 256, 0, stream>>>(y, sc, sh, row_ptr, h);

  // ---------------- GIN 1: x0(64)@off0 -> x1(64)@off64 ----------------
  gather_add_kernel<64><<<N_NODES / 4, 256, 0, stream>>>(h, 0, row_ptr, ssrc, agg);
  ZZ(sum, 8192);
  mfma_gemm_kernel<<<dim3(1, N_NODES / 128), 256, 0, stream>>>(
      h, 512, agg, 64, nullptr, nullptr, g1WtH, g1WtL, g1b, ytemp, 64, sum, sq, N_NODES, 64, 64);
  finstats_kernel<<<1, 1024, 0, stream>>>(sum, sq, 1.f / N_NODES, g1g, g1be, sc, sh, 64);
  ZZ(sum, 8192);
  act_stats_kernel<<<512, 256, 0, stream>>>(ytemp, sc, sh, sum, sq, N_NODES * 64, 63);
  finstats_kernel<<<1, 1024, 0, stream>>>(sum, sq, 1.f / N_NODES, bn1g, bn1be, sc, sh, 64);
  apply_bn_kernel<<<1024, 256, 0, stream>>>(ytemp, sc, sh, h, 64, 6, 63, N_NODES * 64);

  // ---------------- GIN 2: x1(64)@off64 -> x2(128)@off128 ----------------
  gather_add_kernel<64><<<N_NODES / 4, 256, 0, stream>>>(h, 64, row_ptr, ssrc, agg);
  ZZ(sum, 8192);
  mfma_gemm_kernel<<<dim3(2, N_NODES / 128), 256, 0, stream>>>(
      h + 64, 512, agg, 64, nullptr, nullptr, g2WtH, g2WtL, g2b, ytemp, 128, sum, sq, N_NODES, 64, 128);
  finstats_kernel<<<1, 1024, 0, stream>>>(sum, sq, 1.f / N_NODES, g2g, g2be, sc, sh, 128);
  ZZ(sum, 8192);
  act_stats_kernel<<<512, 256, 0, stream>>>(ytemp, sc, sh, sum, sq, N_NODES * 128, 127);
  finstats_kernel<<<1, 1024, 0, stream>>>(sum, sq, 1.f / N_NODES, bn2g, bn2be, sc, sh, 128);
  apply_bn_kernel<<<1024, 256, 0, stream>>>(ytemp, sc, sh, h, 128, 7, 127, N_NODES * 128);

  // ---------------- GIN 3: x2(128)@off128 -> x3(256)@off256 ----------------
  gather_add_kernel<128><<<N_NODES / 4, 256, 0, stream>>>(h, 128, row_ptr, ssrc, agg);
  ZZ(sum, 8192);
  mfma_gemm_kernel<<<dim3(4, N_NODES / 128), 256, 0, stream>>>(
      h + 128, 512, agg, 128, nullptr, nullptr, g3WtH, g3WtL, g3b, ytemp, 256, sum, sq, N_NODES, 128, 256);
  finstats_kernel<<<1, 1024, 0, stream>>>(sum, sq, 1.f / N_NODES, g3g, g3be, sc, sh, 256);
  ZZ(sum, 8192);
  act_stats_kernel<<<512, 256, 0, stream>>>(ytemp, sc, sh, sum, sq, N_NODES * 256, 255);
  finstats_kernel<<<1, 1024, 0, stream>>>(sum, sq, 1.f / N_NODES, bn3g, bn3be, sc, sh, 256);
  apply_bn_kernel<<<1024, 256, 0, stream>>>(ytemp, sc, sh, h, 256, 8, 255, N_NODES * 256);

  // ---------------- lin: [N,512] @ [512,1024] + stats; pool ----------------
  ZZ(sum, 8192);
  mfma_gemm_kernel<<<dim3(16, N_NODES / 128), 256, 0, stream>>>(
      h, 512, nullptr, 0, nullptr, nullptr, linWtH, linWtL, linb, hl, 1024, sum, sq, N_NODES, 512, 1024);
  finstats_kernel<<<1, 1024, 0, stream>>>(sum, sq, 1.f / N_NODES, ling, linbe, sc, sh, 1024);
  pool_kernel<<<dim3(64, 4), 256, 0, stream>>>(hl, sc, sh, o_);

  // ---------------- head (fp32, M=64) ----------------
  ZZ(sum, 8192);
  gemm_bn_kernel<4, 4><<<dim3(1, 8), 256, 0, stream>>>(
      o_, 2048, nullptr, 0, nullptr, nullptr, h1W, h1b, yh1, 512, sum, sq, 64, 2048, 512);
  finstats_kernel<<<1, 1024, 0, stream>>>(sum, sq, 1.f / 64, h1g, h1be, sc, sh, 512);
  ZZ(sum, 8192);
  gemm_bn_kernel<4, 4><<<dim3(1, 4), 256, 0, stream>>>(
      yh1, 512, nullptr, 0, sc, sh, h2W, h2b, yh2, 256, sum, sq, 64, 512, 256);
  finstats_kernel<<<1, 1024, 0, stream>>>(sum, sq, 1.f / 64, h2g, h2be, sc, sh, 256);
  gemm_bn_kernel<4, 4><<<dim3(1, 1), 256, 0, stream>>>(
      yh2, 256, nullptr, 0, sc, sh, outW, outb, logits, 40, nullptr, nullptr, 64, 256, 40);
  lsm_kernel<<<64, 64, 0, stream>>>(logits, (float*)d_out);
#undef ZZ
}

// Round 7
// 1294.114 us; speedup vs baseline: 1.7619x; 1.1199x over previous
//
#include <hip/hip_runtime.h>
#include <math.h>

#define E_EDGES 524288
#define N_NODES 32768
#define N_GRAPHS 64
#define NPG 512

typedef unsigned long long u64;
using bf16x8 = __attribute__((ext_vector_type(8))) short;
using f16x8  = __attribute__((ext_vector_type(8))) _Float16;
using f32x4  = __attribute__((ext_vector_type(4))) float;

__device__ __forceinline__ unsigned short f2bf(float f) {
  unsigned int u = __float_as_uint(f);
  u += 0x7FFFu + ((u >> 16) & 1u);
  return (unsigned short)(u >> 16);
}
__device__ __forceinline__ float b2f(unsigned short s) {
  return __uint_as_float(((unsigned int)s) << 16);
}

// ================= CSR build (dst-sorted edge permutation) =================
__global__ __launch_bounds__(256) void hist_kernel(
    const int* __restrict__ dst, int* __restrict__ cnt)
{
  int e = blockIdx.x * 256 + threadIdx.x;
  atomicAdd(&cnt[dst[e]], 1);
}

__global__ __launch_bounds__(1024) void scan_kernel(
    const int* __restrict__ cnt, int* __restrict__ row_ptr)
{
  __shared__ int s[1024];
  int t = threadIdx.x;
  int base = t * 32;
  int local[32];
  int acc = 0;
#pragma unroll
  for (int i = 0; i < 32; ++i) { local[i] = acc; acc += cnt[base + i]; }
  s[t] = acc;
  __syncthreads();
  for (int d = 1; d < 1024; d <<= 1) {
    int v = (t >= d) ? s[t - d] : 0;
    __syncthreads();
    s[t] += v;
    __syncthreads();
  }
  int off = t ? s[t - 1] : 0;
#pragma unroll
  for (int i = 0; i < 32; ++i) row_ptr[base + i] = off + local[i];
  if (t == 1023) row_ptr[32768] = off + acc;
}

__global__ __launch_bounds__(256) void copy_kernel(
    const int* __restrict__ a, int* __restrict__ b)
{
  int i = blockIdx.x * 256 + threadIdx.x;
  b[i] = a[i];
}

__global__ __launch_bounds__(256) void fill_kernel(
    const int* __restrict__ src, const int* __restrict__ dst,
    int* __restrict__ pos, int* __restrict__ ssrc, int* __restrict__ sdst)
{
  int e = blockIdx.x * 256 + threadIdx.x;
  int d = dst[e];
  int p = atomicAdd(&pos[d], 1);
  ssrc[p] = src[e];
  sdst[p] = d;
}

// ---------------- weight transpose + split-bf16 cast (gin/lin) ----------------
__global__ __launch_bounds__(256) void wt_kernel(
    const float* __restrict__ W, unsigned short* __restrict__ Wt_hi,
    unsigned short* __restrict__ Wt_lo, int kshift, int N, int total)
{
  int idx = blockIdx.x * 256 + threadIdx.x;
  if (idx >= total) return;
  int n = idx >> kshift;
  int k = idx & ((1 << kshift) - 1);
  float w = W[(u64)k * N + n];
  unsigned short hi = f2bf(w);
  Wt_hi[idx] = hi;
  Wt_lo[idx] = f2bf(w - b2f(hi));
}

// ---------------- weight transpose + split-fp16 cast (EC, 64x64) ---------------
__global__ __launch_bounds__(256) void wt16_kernel(
    const float* __restrict__ W, _Float16* __restrict__ Wt_hi,
    _Float16* __restrict__ Wt_lo)
{
  int idx = blockIdx.x * 256 + threadIdx.x;  // 4096
  int n = idx >> 6;
  int k = idx & 63;
  float w = W[k * 64 + n];
  _Float16 hi = (_Float16)w;
  Wt_hi[idx] = hi;
  Wt_lo[idx] = (_Float16)(w - (float)hi);
}

// ---------------- EdgeConv layer 1 (sorted edges), fp16 out + fp32 stats -------
__global__ __launch_bounds__(256) void ec1_kernel(
    const float* __restrict__ x, const int* __restrict__ src, const int* __restrict__ dst,
    const float* __restrict__ W, const float* __restrict__ b,
    _Float16* __restrict__ y, float* __restrict__ sum, float* __restrict__ sq)
{
  __shared__ float Ws[512];
  __shared__ float bs[64];
  __shared__ float red[256];
  int tid = threadIdx.x;
  for (int i = tid; i < 512; i += 256) Ws[i] = W[i];
  if (tid < 64) bs[tid] = b[tid];
  __syncthreads();
  int c = tid & 63;
  int eslot = tid >> 6;
  float ls = 0.f, lq = 0.f;
  int stride = gridDim.x * 4;
  for (int e = blockIdx.x * 4 + eslot; e < E_EDGES; e += stride) {
    int s = src[e], d = dst[e];
    float m[8];
#pragma unroll
    for (int k = 0; k < 4; ++k) {
      float xi = x[d * 4 + k];
      float xj = x[s * 4 + k];
      m[k] = xi; m[4 + k] = xj - xi;
    }
    float acc = bs[c];
#pragma unroll
    for (int k = 0; k < 8; ++k) acc = fmaf(m[k], Ws[k * 64 + c], acc);
    y[(u64)e * 64 + c] = (_Float16)acc;
    ls += acc; lq += acc * acc;
  }
  red[tid] = ls; __syncthreads();
  if (tid < 64) atomicAdd(&sum[tid], red[tid] + red[tid + 64] + red[tid + 128] + red[tid + 192]);
  __syncthreads();
  red[tid] = lq; __syncthreads();
  if (tid < 64) atomicAdd(&sq[tid], red[tid] + red[tid + 64] + red[tid + 128] + red[tid + 192]);
}

// ---------------- stats -> scale/shift (fp32 + fp16 copies) ----------------
__global__ void finstats_kernel(const float* __restrict__ sum, const float* __restrict__ sq,
                                float invcnt, const float* __restrict__ g, const float* __restrict__ be,
                                float* __restrict__ sc, float* __restrict__ sh,
                                _Float16* __restrict__ scH, _Float16* __restrict__ shH, int C)
{
  int c = threadIdx.x + blockIdx.x * blockDim.x;
  if (c >= C) return;
  float m = sum[c] * invcnt;
  float v = sq[c] * invcnt - m * m;
  float inv = rsqrtf(v + 1e-5f);
  float s = g[c] * inv;
  float b = fmaf(-m, s, be[c]);
  sc[c] = s;
  sh[c] = b;
  scH[c] = (_Float16)s;
  shH[c] = (_Float16)b;
}

// -------- fp16 MFMA GEMM for EC layers: Y = relu(A*sc+sh) @ Wt^T + bias --------
// A fp16 [M,64] (dst-sorted edge acts); Wt hi/lo fp16 [64,64]; Y fp16 in-place OK
// (each wave reads/writes only its own 32 rows). BN+ReLU applied in packed fp16.
__global__ __launch_bounds__(256) void mfma_gemm_f16_kernel(
    const _Float16* A,
    const _Float16* __restrict__ scH, const _Float16* __restrict__ shH,
    const _Float16* __restrict__ WtH, const _Float16* __restrict__ WtL,
    const float* __restrict__ bias,
    _Float16* Y,
    float* __restrict__ sum, float* __restrict__ sq)
{
  __shared__ _Float16 BsH[64][72];
  __shared__ _Float16 BsL[64][72];
  __shared__ float redY[64];
  __shared__ float redQ[64];
  int tid = threadIdx.x;
  int lane = tid & 63, wid = tid >> 6;
  int row0 = blockIdx.x * 128 + wid * 32;
  int m16 = lane & 15, quad = lane >> 4;

  // stage B (once; K=64)
#pragma unroll
  for (int it = 0; it < 2; ++it) {
    int slot = tid + it * 256;
    int n = slot >> 3, cg = slot & 7;
    *(uint4*)&BsH[n][cg * 8] = *(const uint4*)(WtH + n * 64 + cg * 8);
    *(uint4*)&BsL[n][cg * 8] = *(const uint4*)(WtL + n * 64 + cg * 8);
  }

  // A fragments: direct fp16 load + packed BN+ReLU
  f16x8 af[2][2];
#pragma unroll
  for (int rt = 0; rt < 2; ++rt) {
    int grow = row0 + rt * 16 + m16;
    const _Float16* ap = A + (u64)grow * 64 + quad * 8;
#pragma unroll
    for (int ks2 = 0; ks2 < 2; ++ks2) {
      f16x8 a = *(const f16x8*)(ap + ks2 * 32);
      f16x8 s8 = *(const f16x8*)(scH + quad * 8 + ks2 * 32);
      f16x8 h8 = *(const f16x8*)(shH + quad * 8 + ks2 * 32);
      a = a * s8 + h8;
#pragma unroll
      for (int j = 0; j < 8; ++j) a[j] = (a[j] > (_Float16)0) ? a[j] : (_Float16)0;
      af[rt][ks2] = a;
    }
  }
  __syncthreads();

  f32x4 acc[2][4];
#pragma unroll
  for (int i = 0; i < 2; ++i)
#pragma unroll
    for (int j = 0; j < 4; ++j) acc[i][j] = {0.f, 0.f, 0.f, 0.f};

#pragma unroll
  for (int ks2 = 0; ks2 < 2; ++ks2) {
#pragma unroll
    for (int ct = 0; ct < 4; ++ct) {
      f16x8 bh = *(const f16x8*)&BsH[ct * 16 + m16][ks2 * 32 + quad * 8];
      f16x8 bl = *(const f16x8*)&BsL[ct * 16 + m16][ks2 * 32 + quad * 8];
#pragma unroll
      for (int rt = 0; rt < 2; ++rt) {
        acc[rt][ct] = __builtin_amdgcn_mfma_f32_16x16x32_f16(af[rt][ks2], bh, acc[rt][ct], 0, 0, 0);
        acc[rt][ct] = __builtin_amdgcn_mfma_f32_16x16x32_f16(af[rt][ks2], bl, acc[rt][ct], 0, 0, 0);
      }
    }
  }

  // epilogue: bias, fp16 store, fp32 stats
  float cys[4], cqs[4];
#pragma unroll
  for (int ct = 0; ct < 4; ++ct) {
    int col = ct * 16 + m16;
    float bcol = bias[col];
    float cy = 0.f, cq = 0.f;
#pragma unroll
    for (int rt = 0; rt < 2; ++rt) {
#pragma unroll
      for (int rg = 0; rg < 4; ++rg) {
        int row = row0 + rt * 16 + quad * 4 + rg;
        float v = acc[rt][ct][rg] + bcol;
        Y[(u64)row * 64 + col] = (_Float16)v;
        cy += v; cq += v * v;
      }
    }
    cys[ct] = cy; cqs[ct] = cq;
  }
#pragma unroll
  for (int ct = 0; ct < 4; ++ct) {
    cys[ct] += __shfl_xor(cys[ct], 16, 64); cys[ct] += __shfl_xor(cys[ct], 32, 64);
    cqs[ct] += __shfl_xor(cqs[ct], 16, 64); cqs[ct] += __shfl_xor(cqs[ct], 32, 64);
  }
  __syncthreads();
  if (tid < 64) { redY[tid] = 0.f; redQ[tid] = 0.f; }
  __syncthreads();
  if (quad == 0) {
#pragma unroll
    for (int ct = 0; ct < 4; ++ct) {
      atomicAdd(&redY[ct * 16 + m16], cys[ct]);
      atomicAdd(&redQ[ct * 16 + m16], cqs[ct]);
    }
  }
  __syncthreads();
  if (tid < 64) {
    atomicAdd(&sum[tid], redY[tid]);
    atomicAdd(&sq[tid], redQ[tid]);
  }
}

// ---------------- split-bf16 MFMA GEMM (fp32 A; gin + lin) ----------------
__global__ __launch_bounds__(256) void mfma_gemm_kernel(
    const float* A, int lda,
    const float* __restrict__ Add, int ldadd,
    const unsigned short* __restrict__ Wt_hi, const unsigned short* __restrict__ Wt_lo,
    const float* __restrict__ bias,
    void* Yptr, int ldy, int y_f16,
    float* __restrict__ sum, float* __restrict__ sq,
    int M, int K, int N)
{
  __shared__ unsigned short BsH[64][72];
  __shared__ unsigned short BsL[64][72];
  __shared__ float redY[64];
  __shared__ float redQ[64];
  int tid = threadIdx.x;
  int lane = tid & 63, wid = tid >> 6;
  int row0 = blockIdx.y * 128 + wid * 32;
  int col0 = blockIdx.x * 64;
  int m16 = lane & 15, quad = lane >> 4;

  f32x4 acc[2][4];
#pragma unroll
  for (int i = 0; i < 2; ++i)
#pragma unroll
    for (int j = 0; j < 4; ++j) acc[i][j] = {0.f, 0.f, 0.f, 0.f};

  for (int k0 = 0; k0 < K; k0 += 64) {
    if (k0) __syncthreads();
#pragma unroll
    for (int it = 0; it < 2; ++it) {
      int slot = tid + it * 256;
      int n = slot >> 3, cg = slot & 7;
      u64 off = (u64)(col0 + n) * K + k0 + cg * 8;
      *(uint4*)&BsH[n][cg * 8] = *(const uint4*)(Wt_hi + off);
      *(uint4*)&BsL[n][cg * 8] = *(const uint4*)(Wt_lo + off);
    }
    __syncthreads();

    bf16x8 ah[2][2], al[2][2];
#pragma unroll
    for (int rt = 0; rt < 2; ++rt) {
      int grow = row0 + rt * 16 + m16;
      const float* ap = A + (u64)grow * lda + k0 + quad * 8;
      const float* addp = Add ? (Add + (u64)grow * ldadd + k0 + quad * 8) : nullptr;
#pragma unroll
      for (int ks2 = 0; ks2 < 2; ++ks2) {
        float4 v0 = *(const float4*)(ap + ks2 * 32);
        float4 v1 = *(const float4*)(ap + ks2 * 32 + 4);
        if (Add) {
          float4 a0 = *(const float4*)(addp + ks2 * 32);
          float4 a1 = *(const float4*)(addp + ks2 * 32 + 4);
          v0.x += a0.x; v0.y += a0.y; v0.z += a0.z; v0.w += a0.w;
          v1.x += a1.x; v1.y += a1.y; v1.z += a1.z; v1.w += a1.w;
        }
        float f[8] = {v0.x, v0.y, v0.z, v0.w, v1.x, v1.y, v1.z, v1.w};
        bf16x8 th, tl;
#pragma unroll
        for (int j = 0; j < 8; ++j) {
          unsigned short hi = f2bf(f[j]);
          th[j] = (short)hi;
          tl[j] = (short)f2bf(f[j] - b2f(hi));
        }
        ah[rt][ks2] = th;
        al[rt][ks2] = tl;
      }
    }

#pragma unroll
    for (int ks2 = 0; ks2 < 2; ++ks2) {
#pragma unroll
      for (int ct = 0; ct < 4; ++ct) {
        bf16x8 bh = *(const bf16x8*)&BsH[ct * 16 + m16][ks2 * 32 + quad * 8];
        bf16x8 bl = *(const bf16x8*)&BsL[ct * 16 + m16][ks2 * 32 + quad * 8];
#pragma unroll
        for (int rt = 0; rt < 2; ++rt) {
          acc[rt][ct] = __builtin_amdgcn_mfma_f32_16x16x32_bf16(ah[rt][ks2], bh, acc[rt][ct], 0, 0, 0);
          acc[rt][ct] = __builtin_amdgcn_mfma_f32_16x16x32_bf16(ah[rt][ks2], bl, acc[rt][ct], 0, 0, 0);
          acc[rt][ct] = __builtin_amdgcn_mfma_f32_16x16x32_bf16(al[rt][ks2], bh, acc[rt][ct], 0, 0, 0);
        }
      }
    }
  }

  float cys[4], cqs[4];
#pragma unroll
  for (int ct = 0; ct < 4; ++ct) {
    int col = col0 + ct * 16 + m16;
    float bcol = bias[col];
    float cy = 0.f, cq = 0.f;
#pragma unroll
    for (int rt = 0; rt < 2; ++rt) {
#pragma unroll
      for (int rg = 0; rg < 4; ++rg) {
        int row = row0 + rt * 16 + quad * 4 + rg;
        float v = acc[rt][ct][rg] + bcol;
        if (y_f16) ((_Float16*)Yptr)[(u64)row * ldy + col] = (_Float16)v;
        else       ((float*)Yptr)[(u64)row * ldy + col] = v;
        cy += v; cq += v * v;
      }
    }
    cys[ct] = cy; cqs[ct] = cq;
  }
  if (sum) {
#pragma unroll
    for (int ct = 0; ct < 4; ++ct) {
      cys[ct] += __shfl_xor(cys[ct], 16, 64); cys[ct] += __shfl_xor(cys[ct], 32, 64);
      cqs[ct] += __shfl_xor(cqs[ct], 16, 64); cqs[ct] += __shfl_xor(cqs[ct], 32, 64);
    }
    __syncthreads();
    if (tid < 64) { redY[tid] = 0.f; redQ[tid] = 0.f; }
    __syncthreads();
    if (quad == 0) {
#pragma unroll
      for (int ct = 0; ct < 4; ++ct) {
        atomicAdd(&redY[ct * 16 + m16], cys[ct]);
        atomicAdd(&redQ[ct * 16 + m16], cqs[ct]);
      }
    }
    __syncthreads();
    if (tid < 64) {
      atomicAdd(&sum[col0 + tid], redY[tid]);
      atomicAdd(&sq[col0 + tid], redQ[tid]);
    }
  }
}

// ---------------- head GEMM: M=64 rows, one row per block ----------------
// Y[r,c] = bias[c] + sum_k preact(A[r,k]) * W[k,c];  grid (Cout/256, 64)
__global__ __launch_bounds__(256) void head_gemm_kernel(
    const float* __restrict__ A, int K,
    const float* __restrict__ preSc, const float* __restrict__ preSh,
    const float* __restrict__ W, const float* __restrict__ bias,
    float* __restrict__ Y, int Cout,
    float* __restrict__ sum, float* __restrict__ sq)
{
  __shared__ float As[2048];
  int r = blockIdx.y;
  int tid = threadIdx.x;
  for (int k = tid; k < K; k += 256) {
    float v = A[(u64)r * K + k];
    if (preSc) v = fmaxf(fmaf(v, preSc[k], preSh[k]), 0.f);
    As[k] = v;
  }
  __syncthreads();
  int c = blockIdx.x * 256 + tid;
  if (c >= Cout) return;
  float a0 = 0.f, a1 = 0.f, a2 = 0.f, a3 = 0.f;
  for (int k = 0; k < K; k += 4) {
    a0 = fmaf(As[k + 0], W[(u64)(k + 0) * Cout + c], a0);
    a1 = fmaf(As[k + 1], W[(u64)(k + 1) * Cout + c], a1);
    a2 = fmaf(As[k + 2], W[(u64)(k + 2) * Cout + c], a2);
    a3 = fmaf(As[k + 3], W[(u64)(k + 3) * Cout + c], a3);
  }
  float acc = bias[c] + ((a0 + a1) + (a2 + a3));
  Y[(u64)r * Cout + c] = acc;
  if (sum) { atomicAdd(&sum[c], acc); atomicAdd(&sq[c], acc * acc); }
}

// ---------------- in-place act (bn+relu) + stats of result ----------------
__global__ __launch_bounds__(256) void act_stats_kernel(
    float* __restrict__ y, const float* __restrict__ sc, const float* __restrict__ sh,
    float* __restrict__ sum, float* __restrict__ sq, int total, int cmask)
{
  __shared__ float red[256];
  int tid = threadIdx.x;
  int c = tid & cmask;
  float s = sc[c], b = sh[c];
  float ls = 0.f, lq = 0.f;
  for (int idx = blockIdx.x * 256 + tid; idx < total; idx += gridDim.x * 256) {
    float v = fmaxf(fmaf(y[idx], s, b), 0.f);
    y[idx] = v;
    ls += v; lq += v * v;
  }
  red[tid] = ls; __syncthreads();
  if (tid <= cmask) {
    float t = 0.f;
    for (int k = tid; k < 256; k += cmask + 1) t += red[k];
    atomicAdd(&sum[tid], t);
  }
  __syncthreads();
  red[tid] = lq; __syncthreads();
  if (tid <= cmask) {
    float t = 0.f;
    for (int k = tid; k < 256; k += cmask + 1) t += red[k];
    atomicAdd(&sq[tid], t);
  }
}

// ---------------- apply outer BN into h slice ----------------
__global__ __launch_bounds__(256) void apply_bn_kernel(
    const float* __restrict__ a, const float* __restrict__ sc, const float* __restrict__ sh,
    float* __restrict__ h, int off, int cshift, int cmask, int total)
{
  for (int idx = blockIdx.x * 256 + threadIdx.x; idx < total; idx += gridDim.x * 256) {
    int r = idx >> cshift;
    int c = idx & cmask;
    h[(u64)r * 512 + off + c] = fmaf(a[idx], sc[c], sh[c]);
  }
}

// ------------- EdgeConv segment_max via CSR (y fp16, dst-sorted) ----------------
__global__ __launch_bounds__(256) void x0max_csr_kernel(
    const _Float16* __restrict__ y3, const float* __restrict__ sc, const float* __restrict__ sh,
    const int* __restrict__ row_ptr, float* __restrict__ h)
{
  int n = blockIdx.x * 4 + (threadIdx.x >> 6);
  int lane = threadIdx.x & 63;
  int b = row_ptr[n], e = row_ptr[n + 1];
  float s = sc[lane], bb = sh[lane];
  float mx = 0.f;
  for (int i = b; i < e; ++i) {
    float v = fmaxf(fmaf((float)y3[(u64)i * 64 + lane], s, bb), 0.f);
    mx = fmaxf(mx, v);
  }
  h[(u64)n * 512 + lane] = mx;
}

// ------------- GIN neighbor-sum via CSR gather ----------------
template<int COLS>
__global__ __launch_bounds__(256) void gather_add_kernel(
    const float* __restrict__ h, int off,
    const int* __restrict__ row_ptr, const int* __restrict__ ssrc,
    float* __restrict__ agg)
{
  int n = blockIdx.x * 4 + (threadIdx.x >> 6);
  int lane = threadIdx.x & 63;
  int b = row_ptr[n], e = row_ptr[n + 1];
  float a0 = 0.f, a1 = 0.f;
  for (int i = b; i < e; ++i) {
    const float* p = h + (u64)ssrc[i] * 512 + off + lane;
    a0 += p[0];
    if (COLS > 64) a1 += p[64];
  }
  float* q = agg + (u64)n * COLS + lane;
  q[0] = a0;
  if (COLS > 64) q[64] = a1;
}

// ---------------- graph pooling (hl fp16) ----------------
__global__ __launch_bounds__(256) void pool_kernel(
    const _Float16* __restrict__ hl, const float* __restrict__ sc, const float* __restrict__ sh,
    float* __restrict__ o)
{
  int g = blockIdx.x;
  int c = blockIdx.y * 256 + threadIdx.x;
  float s = sc[c], b = sh[c];
  const _Float16* p = hl + (u64)g * NPG * 1024 + c;
  float mx = 0.f, sm = 0.f;
  for (int n = 0; n < NPG; ++n) {
    float v = fmaxf(fmaf((float)p[(u64)n * 1024], s, b), 0.f);
    mx = fmaxf(mx, v);
    sm += v;
  }
  o[g * 2048 + c] = mx;
  o[g * 2048 + 1024 + c] = sm * (1.f / NPG);
}

// ---------------- log_softmax over 40 cols ----------------
__global__ void lsm_kernel(const float* __restrict__ logits, float* __restrict__ out)
{
  int r = blockIdx.x;
  int c = threadIdx.x;
  float v = (c < 40) ? logits[r * 40 + c] : -INFINITY;
  float m = v;
  for (int off = 32; off; off >>= 1) m = fmaxf(m, __shfl_xor(m, off, 64));
  float e = (c < 40) ? expf(v - m) : 0.f;
  float s = e;
  for (int off = 32; off; off >>= 1) s += __shfl_xor(s, off, 64);
  if (c < 40) out[r * 40 + c] = (v - m) - logf(s);
}

extern "C" void kernel_launch(void* const* d_in, const int* in_sizes, int n_in,
                              void* d_out, int out_size, void* d_ws, size_t ws_size,
                              hipStream_t stream)
{
  const float* x    = (const float*)d_in[0];
  const int*   ei   = (const int*)d_in[1];
  const int*   srcI = ei;
  const int*   dstI = ei + E_EDGES;
  const float* ecW1 = (const float*)d_in[3];
  const float* ecb1 = (const float*)d_in[4];
  const float* ecg1 = (const float*)d_in[5];
  const float* ecbe1= (const float*)d_in[6];
  const float* ecW2 = (const float*)d_in[7];
  const float* ecb2 = (const float*)d_in[8];
  const float* ecg2 = (const float*)d_in[9];
  const float* ecbe2= (const float*)d_in[10];
  const float* ecW3 = (const float*)d_in[11];
  const float* ecb3 = (const float*)d_in[12];
  const float* ecg3 = (const float*)d_in[13];
  const float* ecbe3= (const float*)d_in[14];
  const float* g1W  = (const float*)d_in[15];
  const float* g1b  = (const float*)d_in[16];
  const float* g1g  = (const float*)d_in[17];
  const float* g1be = (const float*)d_in[18];
  const float* g2W  = (const float*)d_in[19];
  const float* g2b  = (const float*)d_in[20];
  const float* g2g  = (const float*)d_in[21];
  const float* g2be = (const float*)d_in[22];
  const float* g3W  = (const float*)d_in[23];
  const float* g3b  = (const float*)d_in[24];
  const float* g3g  = (const float*)d_in[25];
  const float* g3be = (const float*)d_in[26];
  const float* bn1g = (const float*)d_in[27];
  const float* bn1be= (const float*)d_in[28];
  const float* bn2g = (const float*)d_in[29];
  const float* bn2be= (const float*)d_in[30];
  const float* bn3g = (const float*)d_in[31];
  const float* bn3be= (const float*)d_in[32];
  const float* linW = (const float*)d_in[33];
  const float* linb = (const float*)d_in[34];
  const float* ling = (const float*)d_in[35];
  const float* linbe= (const float*)d_in[36];
  const float* h1W  = (const float*)d_in[37];
  const float* h1b  = (const float*)d_in[38];
  const float* h1g  = (const float*)d_in[39];
  const float* h1be = (const float*)d_in[40];
  const float* h2W  = (const float*)d_in[41];
  const float* h2b  = (const float*)d_in[42];
  const float* h2g  = (const float*)d_in[43];
  const float* h2be = (const float*)d_in[44];
  const float* outW = (const float*)d_in[45];
  const float* outb = (const float*)d_in[46];

  char* ws = (char*)d_ws;
  const size_t MB = 1024ull * 1024ull;
  // ---- small area [0, 1 MiB) ----
  float* sum    = (float*)(ws);
  float* sq     = (float*)(ws + 4096);
  float* sc     = (float*)(ws + 8192);
  float* sh     = (float*)(ws + 12288);
  _Float16* scH = (_Float16*)(ws + 16384);
  _Float16* shH = (_Float16*)(ws + 20480);
  float* o_     = (float*)(ws + 32768);                    // [64,2048] 512 KiB
  float* yh1    = (float*)(ws + 32768 + 524288);           // [64,512]
  float* yh2    = (float*)(ws + 32768 + 524288 + 131072);  // [64,256]
  float* logits = (float*)(ws + 32768 + 524288 + 131072 + 65536);
  // ---- weights [1 MiB, 4 MiB) ----
  _Float16* ec2WtH16 = (_Float16*)(ws + 1 * MB);
  _Float16* ec2WtL16 = (_Float16*)(ws + 1 * MB + 8192);
  _Float16* ec3WtH16 = (_Float16*)(ws + 1 * MB + 16384);
  _Float16* ec3WtL16 = (_Float16*)(ws + 1 * MB + 24576);
  unsigned short* g1WtH  = (unsigned short*)(ws + 1 * MB + 32768);
  unsigned short* g1WtL  = (unsigned short*)(ws + 1 * MB + 40960);
  unsigned short* g2WtH  = (unsigned short*)(ws + 1 * MB + 49152);
  unsigned short* g2WtL  = (unsigned short*)(ws + 1 * MB + 65536);
  unsigned short* g3WtH  = (unsigned short*)(ws + 1 * MB + 81920);
  unsigned short* g3WtL  = (unsigned short*)(ws + 1 * MB + 147456);
  unsigned short* linWtH = (unsigned short*)(ws + 1 * MB + 212992);
  unsigned short* linWtL = (unsigned short*)(ws + 1 * MB + 212992 + 1048576);
  // ---- big region [4 MiB, 132 MiB): y fp16 [E,64] (64 MiB);
  //      then ytemp fp32 (32 MiB) + agg fp32 @ +32 MiB; then hl fp16 [N,1024] (64 MiB)
  _Float16* y  = (_Float16*)(ws + 4 * MB);
  float* ytemp = (float*)(ws + 4 * MB);
  float* agg   = (float*)(ws + 36 * MB);
  _Float16* hl = (_Float16*)(ws + 4 * MB);
  // ---- h region [132 MiB, 196 MiB): [N,512] fp32 concat buffer ----
  float* h = (float*)(ws + 132 * MB);
  // ---- CSR region [196 MiB, 201 MiB) ----
  int* row_ptr = (int*)(ws + 196 * MB);
  int* cnt     = (int*)(ws + 196 * MB + 140000);
  int* ssrc    = (int*)(ws + 197 * MB);
  int* sdst    = (int*)(ws + 199 * MB);

#define ZZ(p, n) hipMemsetAsync((void*)(p), 0, (size_t)(n), stream)
#define FINST(invc, g, be, C) finstats_kernel<<<1, 1024, 0, stream>>>(sum, sq, invc, g, be, sc, sh, scH, shH, C)

  // ---------------- CSR build ----------------
  ZZ(cnt, 32768 * 4);
  hist_kernel<<<2048, 256, 0, stream>>>(dstI, cnt);
  scan_kernel<<<1, 1024, 0, stream>>>(cnt, row_ptr);
  copy_kernel<<<128, 256, 0, stream>>>(row_ptr, cnt);
  fill_kernel<<<2048, 256, 0, stream>>>(srcI, dstI, cnt, ssrc, sdst);

  // ---------------- weight prep ----------------
  wt16_kernel<<<16, 256, 0, stream>>>(ecW2, ec2WtH16, ec2WtL16);
  wt16_kernel<<<16, 256, 0, stream>>>(ecW3, ec3WtH16, ec3WtL16);
  wt_kernel<<<16, 256, 0, stream>>>(g1W, g1WtH, g1WtL, 6, 64, 4096);
  wt_kernel<<<32, 256, 0, stream>>>(g2W, g2WtH, g2WtL, 6, 128, 8192);
  wt_kernel<<<128, 256, 0, stream>>>(g3W, g3WtH, g3WtL, 7, 256, 32768);
  wt_kernel<<<2048, 256, 0, stream>>>(linW, linWtH, linWtL, 9, 1024, 524288);

  // ---------------- EdgeConv (fp16 y, in-place) ----------------
  ZZ(sum, 8192);
  ec1_kernel<<<512, 256, 0, stream>>>(x, ssrc, sdst, ecW1, ecb1, y, sum, sq);
  FINST(1.f / E_EDGES, ecg1, ecbe1, 64);
  ZZ(sum, 8192);
  mfma_gemm_f16_kernel<<<E_EDGES / 128, 256, 0, stream>>>(
      y, scH, shH, ec2WtH16, ec2WtL16, ecb2, y, sum, sq);
  FINST(1.f / E_EDGES, ecg2, ecbe2, 64);
  ZZ(sum, 8192);
  mfma_gemm_f16_kernel<<<E_EDGES / 128, 256, 0, stream>>>(
      y, scH, shH, ec3WtH16, ec3WtL16, ecb3, y, sum, sq);
  FINST(1.f / E_EDGES, ecg3, ecbe3, 64);
  x0max_csr_kernel<<<N_NODES / 4, 256, 0, stream>>>(y, sc, sh, row_ptr, h);

  // ---------------- GIN 1 ----------------
  gather_add_kernel<64><<<N_NODES / 4, 256, 0, stream>>>(h, 0, row_ptr, ssrc, agg);
  ZZ(sum, 8192);
  mfma_gemm_kernel<<<dim3(1, N_NODES / 128), 256, 0, stream>>>(
      h, 512, agg, 64, g1WtH, g1WtL, g1b, ytemp, 64, 0, sum, sq, N_NODES, 64, 64);
  FINST(1.f / N_NODES, g1g, g1be, 64);
  ZZ(sum, 8192);
  act_stats_kernel<<<512, 256, 0, stream>>>(ytemp, sc, sh, sum, sq, N_NODES * 64, 63);
  FINST(1.f / N_NODES, bn1g, bn1be, 64);
  apply_bn_kernel<<<1024, 256, 0, stream>>>(ytemp, sc, sh, h, 64, 6, 63, N_NODES * 64);

  // ---------------- GIN 2 ----------------
  gather_add_kernel<64><<<N_NODES / 4, 256, 0, stream>>>(h, 64, row_ptr, ssrc, agg);
  ZZ(sum, 8192);
  mfma_gemm_kernel<<<dim3(2, N_NODES / 128), 256, 0, stream>>>(
      h + 64, 512, agg, 64, g2WtH, g2WtL, g2b, ytemp, 128, 0, sum, sq, N_NODES, 64, 128);
  FINST(1.f / N_NODES, g2g, g2be, 128);
  ZZ(sum, 8192);
  act_stats_kernel<<<512, 256, 0, stream>>>(ytemp, sc, sh, sum, sq, N_NODES * 128, 127);
  FINST(1.f / N_NODES, bn2g, bn2be, 128);
  apply_bn_kernel<<<1024, 256, 0, stream>>>(ytemp, sc, sh, h, 128, 7, 127, N_NODES * 128);

  // ---------------- GIN 3 ----------------
  gather_add_kernel<128><<<N_NODES / 4, 256, 0, stream>>>(h, 128, row_ptr, ssrc, agg);
  ZZ(sum, 8192);
  mfma_gemm_kernel<<<dim3(4, N_NODES / 128), 256, 0, stream>>>(
      h + 128, 512, agg, 128, g3WtH, g3WtL, g3b, ytemp, 256, 0, sum, sq, N_NODES, 128, 256);
  FINST(1.f / N_NODES, g3g, g3be, 256);
  ZZ(sum, 8192);
  act_stats_kernel<<<512, 256, 0, stream>>>(ytemp, sc, sh, sum, sq, N_NODES * 256, 255);
  FINST(1.f / N_NODES, bn3g, bn3be, 256);
  apply_bn_kernel<<<1024, 256, 0, stream>>>(ytemp, sc, sh, h, 256, 8, 255, N_NODES * 256);

  // ---------------- lin (fp16 output) + pool ----------------
  ZZ(sum, 8192);
  mfma_gemm_kernel<<<dim3(16, N_NODES / 128), 256, 0, stream>>>(
      h, 512, nullptr, 0, linWtH, linWtL, linb, hl, 1024, 1, sum, sq, N_NODES, 512, 1024);
  FINST(1.f / N_NODES, ling, linbe, 1024);
  pool_kernel<<<dim3(64, 4), 256, 0, stream>>>(hl, sc, sh, o_);

  // ---------------- head ----------------
  ZZ(sum, 8192);
  head_gemm_kernel<<<dim3(2, 64), 256, 0, stream>>>(
      o_, 2048, nullptr, nullptr, h1W, h1b, yh1, 512, sum, sq);
  FINST(1.f / 64, h1g, h1be, 512);
  ZZ(sum, 8192);
  head_gemm_kernel<<<dim3(1, 64), 256, 0, stream>>>(
      yh1, 512, sc, sh, h2W, h2b, yh2, 256, sum, sq);
  FINST(1.f / 64, h2g, h2be, 256);
  head_gemm_kernel<<<dim3(1, 64), 256, 0, stream>>>(
      yh2, 256, sc, sh, outW, outb, logits, 40, nullptr, nullptr);
  lsm_kernel<<<64, 64, 0, stream>>>(logits, (float*)d_out);
#undef FINST
#undef ZZ
}